// Round 9
// baseline (266.032 us; speedup 1.0000x reference)
//
#include <hip/hip_runtime.h>
#include <cmath>

#define NB    16
#define TT1   2048
#define TT2   512
#define NATT  256
#define TEMP  0.0005f

// workspace element counts (ushort = bf16 unless noted)
#define KP_SZ   (NB*514*256)        // padded keys (B, 514, 256)
#define H1_SZ   (NB*512*512)        // key conv1 out (relu)
#define KE_SZ   (NB*512*256)        // key proj out
#define QP_SZ   (NB*2050*80)        // padded transposed queries
#define QH1_SZ  (NB*2048*160)
#define QH2_SZ  (NB*2048*80)
#define QE_SZ   (NB*2048*256)
#define W1T_SZ  (512*768)
#define W2T_SZ  (256*512)
#define W3T_SZ  (160*256)
#define W4T_SZ  (80*160)
#define W5T_SZ  (256*96)
#define LGP_SZ  (NB*TT1*TT2)        // bf16 log(prior+eps), transposed [b][t1][t2]
#define K2_SZ   (NB*512)            // f32

typedef __attribute__((ext_vector_type(8))) short short8v;
typedef __attribute__((ext_vector_type(4))) float f32x4;

__device__ inline ushort f2bf(float f) {
    unsigned int u = __float_as_uint(f);
    u += 0x7fff + ((u >> 16) & 1);      // RNE
    return (ushort)(u >> 16);
}
__device__ inline float bf2f(ushort u) {
    return __uint_as_float(((unsigned int)u) << 16);
}

// ---------------- padding / transpose (emit bf16) ----------------

__global__ void pad_keys_kernel(const float* __restrict__ keys, ushort* __restrict__ kp) {
    int idx = blockIdx.x * blockDim.x + threadIdx.x;
    if (idx >= KP_SZ) return;
    int c = idx & 255;
    int r = (idx >> 8) % 514;
    int b = idx / (514 * 256);
    float v = 0.f;
    if (r >= 1 && r <= 512)
        v = keys[((size_t)b * 512 + (r - 1)) * 256 + c];
    kp[idx] = f2bf(v);
}

__global__ void pad_transpose_queries_kernel(const float* __restrict__ q, ushort* __restrict__ qp) {
    int idx = blockIdx.x * blockDim.x + threadIdx.x;
    if (idx >= QP_SZ) return;
    int c = idx % 80;
    int r = (idx / 80) % 2050;
    int b = idx / (2050 * 80);
    float v = 0.f;
    if (r >= 1 && r <= 2048)
        v = q[((size_t)b * 80 + c) * 2048 + (r - 1)];
    qp[idx] = f2bf(v);
}

// ---------------- prior: transpose + log -> bf16 ----------------
// lgp[b][t1][t2] = bf16(log(prior[b][t2][t1] + 1e-8))

__global__ __launch_bounds__(256) void prior_log_transpose(
    const float* __restrict__ prior, ushort* __restrict__ lgp)
{
    __shared__ float T[64][65];
    const int b    = blockIdx.z;
    const int t1_0 = blockIdx.x * 64;
    const int t2_0 = blockIdx.y * 64;
    const int j  = threadIdx.x & 63;
    const int i0 = (threadIdx.x >> 6) * 16;
    #pragma unroll
    for (int r = 0; r < 16; ++r)
        T[i0 + r][j] = prior[((size_t)b * TT2 + t2_0 + i0 + r) * TT1 + t1_0 + j];
    __syncthreads();
    #pragma unroll
    for (int r = 0; r < 16; ++r) {
        const int p = i0 + r;
        const float v = T[j][p];
        lgp[((size_t)b * TT1 + t1_0 + p) * TT2 + t2_0 + j] = f2bf(__logf(v + 1e-8f));
    }
}

// ---------------- weight transpose + bf16 (+ K zero-pad) ----------------

__global__ void wtrans_kernel(const float* __restrict__ w, ushort* __restrict__ wt,
                              int Kreal, int Kpad, int N) {
    int idx = blockIdx.x * blockDim.x + threadIdx.x;
    if (idx >= N * Kpad) return;
    int k = idx % Kpad;
    int n = idx / Kpad;
    wt[idx] = (k < Kreal) ? f2bf(w[(size_t)k * N + n]) : (ushort)0;
}

// ---------------- bf16 MFMA conv-as-GEMM ----------------

template<int KPAD, int N, int MFRAG, int NFRAG, bool RELU>
__global__ __launch_bounds__(256) void mfma_gemm(
    const ushort* __restrict__ A, const ushort* __restrict__ Wt,
    const float* __restrict__ bias, ushort* __restrict__ C,
    int Tdim, int bStride, int rowStride)
{
    const int tid  = threadIdx.x;
    const int wv   = tid >> 6;
    const int lane = tid & 63;
    const int lr   = lane & 15;
    const int lk   = lane >> 4;
    const int m0   = blockIdx.x * (64 * MFRAG);
    const int n0   = blockIdx.y * (NFRAG * 16);

    const ushort* arow[MFRAG];
    #pragma unroll
    for (int mf = 0; mf < MFRAG; ++mf) {
        const int m = m0 + (wv * MFRAG + mf) * 16 + lr;
        arow[mf] = A + (size_t)(m / Tdim) * bStride
                     + (size_t)(m % Tdim) * rowStride + lk * 8;
    }
    const ushort* wtb = Wt + (size_t)(n0 + lr) * KPAD + lk * 8;

    f32x4 acc[MFRAG][NFRAG];
    #pragma unroll
    for (int mf = 0; mf < MFRAG; ++mf)
        #pragma unroll
        for (int f = 0; f < NFRAG; ++f) acc[mf][f] = (f32x4){0.f, 0.f, 0.f, 0.f};

    #pragma unroll
    for (int ks = 0; ks < KPAD / 32; ++ks) {
        short8v a[MFRAG];
        #pragma unroll
        for (int mf = 0; mf < MFRAG; ++mf)
            a[mf] = *(const short8v*)(arow[mf] + ks * 32);
        #pragma unroll
        for (int f = 0; f < NFRAG; ++f) {
            const short8v b = *(const short8v*)(wtb + (size_t)f * 16 * KPAD + ks * 32);
            #pragma unroll
            for (int mf = 0; mf < MFRAG; ++mf)
                acc[mf][f] = __builtin_amdgcn_mfma_f32_16x16x32_bf16(a[mf], b, acc[mf][f], 0, 0, 0);
        }
    }

    // C layout: col = lane&15 (N), row = (lane>>4)*4 + reg (M)
    #pragma unroll
    for (int mf = 0; mf < MFRAG; ++mf) {
        const int orow = m0 + (wv * MFRAG + mf) * 16 + lk * 4;
        #pragma unroll
        for (int f = 0; f < NFRAG; ++f) {
            const int col = n0 + f * 16 + lr;
            const float bv = bias[col];
            #pragma unroll
            for (int r = 0; r < 4; ++r) {
                float o = acc[mf][f][r] + bv;
                if (RELU) o = fmaxf(o, 0.f);
                C[(size_t)(orow + r) * N + col] = f2bf(o);
            }
        }
    }
}

// ---------------- k2t = -TEMP * sum(ke^2) (bf16 input) ----------------

__global__ void k2_kernel(const ushort* __restrict__ ke, float* __restrict__ k2) {
    int row = blockIdx.x * 4 + (threadIdx.x >> 6);   // (b*512 + t2)
    int lane = threadIdx.x & 63;
    ushort4 v = ((const ushort4*)(ke + (size_t)row * 256))[lane];
    float x = bf2f(v.x), y = bf2f(v.y), z = bf2f(v.z), w = bf2f(v.w);
    float ss = x * x + y * y + z * z + w * w;
    #pragma unroll
    for (int off = 32; off; off >>= 1) ss += __shfl_xor(ss, off);
    if (lane == 0) k2[row] = -TEMP * ss;
}

// ---------------- fused attention ----------------
// phase 1: wave w computes s = 2*TEMP*QK^T + k2t for cols [w*64, w*64+64) -> LDS S
// ONE barrier. phase 2: wave w owns rows 2w, 2w+1; lane covers t2 in [lane*8, lane*8+8);
// all reductions via in-wave shuffles; all intermediates in registers.

__device__ __forceinline__ void softmax_row(
    const float* __restrict__ Srow, const int e0,
    const short8v lgv, const unsigned long long mb,
    float* __restrict__ lprow, float* __restrict__ atrow)
{
    float s[8];
    *(float4*)&s[0] = *(const float4*)(Srow + e0);
    *(float4*)&s[4] = *(const float4*)(Srow + e0 + 4);

    // first softmax: logZ over full row
    float mx = fmaxf(fmaxf(fmaxf(s[0], s[1]), fmaxf(s[2], s[3])),
                     fmaxf(fmaxf(s[4], s[5]), fmaxf(s[6], s[7])));
    #pragma unroll
    for (int off = 32; off; off >>= 1) mx = fmaxf(mx, __shfl_xor(mx, off));
    float se = 0.f;
    #pragma unroll
    for (int j = 0; j < 8; ++j) se += __expf(s[j] - mx);
    #pragma unroll
    for (int off = 32; off; off >>= 1) se += __shfl_xor(se, off);
    const float logZ = mx + __logf(se);

    float uu[8], U[8];
    #pragma unroll
    for (int j = 0; j < 8; ++j) {
        uu[j] = s[j] + bf2f((ushort)lgv[j]);
        const bool msk = ((mb >> (8 * j)) & 0xffULL) != 0;
        U[j] = msk ? -INFINITY : uu[j];
    }
    float4 st;
    st.x = uu[0] - logZ; st.y = uu[1] - logZ; st.z = uu[2] - logZ; st.w = uu[3] - logZ;
    *(float4*)(lprow + e0) = st;
    st.x = uu[4] - logZ; st.y = uu[5] - logZ; st.z = uu[6] - logZ; st.w = uu[7] - logZ;
    *(float4*)(lprow + e0 + 4) = st;

    // masked softmax (exp values reused for output)
    float mx2 = fmaxf(fmaxf(fmaxf(U[0], U[1]), fmaxf(U[2], U[3])),
                      fmaxf(fmaxf(U[4], U[5]), fmaxf(U[6], U[7])));
    #pragma unroll
    for (int off = 32; off; off >>= 1) mx2 = fmaxf(mx2, __shfl_xor(mx2, off));
    float ex[8];
    float se2 = 0.f;
    #pragma unroll
    for (int j = 0; j < 8; ++j) { ex[j] = __expf(U[j] - mx2); se2 += ex[j]; }
    #pragma unroll
    for (int off = 32; off; off >>= 1) se2 += __shfl_xor(se2, off);
    const float inv = 1.0f / se2;
    st.x = ex[0] * inv; st.y = ex[1] * inv; st.z = ex[2] * inv; st.w = ex[3] * inv;
    *(float4*)(atrow + e0) = st;
    st.x = ex[4] * inv; st.y = ex[5] * inv; st.z = ex[6] * inv; st.w = ex[7] * inv;
    *(float4*)(atrow + e0 + 4) = st;
}

__global__ __launch_bounds__(512) void attn_kernel(
    const ushort* __restrict__ qe, const ushort* __restrict__ ke,
    const float* __restrict__ k2t, const ushort* __restrict__ lgp,
    const unsigned char* __restrict__ mask,
    float* __restrict__ out_attn, float* __restrict__ out_lp)
{
    __shared__ float S[16][520];
    const int b    = blockIdx.x >> 7;
    const int t1_0 = (blockIdx.x & 127) << 4;
    const int tid  = threadIdx.x;
    const int lane = tid & 63;
    const int wv   = tid >> 6;

    // ---- prefetch for phase 2 (this wave's rows; consumed after barrier) ----
    const int e0 = lane << 3;                 // 8 t2 elems per lane
    const int r0 = wv << 1;
    const short8v lgv0 = *(const short8v*)(lgp + ((size_t)b * TT1 + t1_0 + r0) * TT2 + e0);
    const short8v lgv1 = *(const short8v*)(lgp + ((size_t)b * TT1 + t1_0 + r0 + 1) * TT2 + e0);
    const unsigned long long mb = *(const unsigned long long*)(mask + (size_t)b * TT2 + e0);

    // ---- phase 1: QK^T via MFMA, fold k2t ----
    {
        const int lr = lane & 15;
        const int lk = lane >> 4;
        const ushort* qrow = qe + ((size_t)b * TT1 + t1_0 + lr) * NATT + lk * 8;
        short8v a[8];
        #pragma unroll
        for (int k = 0; k < 8; ++k)
            a[k] = *(const short8v*)(qrow + k * 32);

        const ushort* kbase = ke + ((size_t)b * TT2 + wv * 64 + lr) * NATT + lk * 8;
        #pragma unroll
        for (int n = 0; n < 4; ++n) {
            f32x4 acc = {0.f, 0.f, 0.f, 0.f};
            const ushort* kb = kbase + (size_t)n * 16 * NATT;
            #pragma unroll
            for (int k = 0; k < 8; ++k) {
                short8v bfr = *(const short8v*)(kb + k * 32);
                acc = __builtin_amdgcn_mfma_f32_16x16x32_bf16(a[k], bfr, acc, 0, 0, 0);
            }
            const int col = wv * 64 + n * 16 + lr;
            const float k2v = k2t[(size_t)b * TT2 + col];
            #pragma unroll
            for (int r = 0; r < 4; ++r)
                S[lk * 4 + r][col] = fmaf(2.0f * TEMP, acc[r], k2v);
        }
    }
    __syncthreads();

    // ---- phase 2: per-wave rows, register-resident softmax pipeline ----
    float* lp0 = out_lp   + ((size_t)b * TT1 + t1_0 + r0) * TT2;
    float* at0 = out_attn + ((size_t)b * TT1 + t1_0 + r0) * TT2;
    softmax_row(&S[r0][0],     e0, lgv0, mb, lp0,       at0);
    softmax_row(&S[r0 + 1][0], e0, lgv1, mb, lp0 + TT2, at0 + TT2);
}

// ---------------- launch ----------------

extern "C" void kernel_launch(void* const* d_in, const int* in_sizes, int n_in,
                              void* d_out, int out_size, void* d_ws, size_t ws_size,
                              hipStream_t stream) {
    const float* queries = (const float*)d_in[0];   // (B, 80, 2048)
    const float* keys    = (const float*)d_in[1];   // (B, 512, 256)
    const unsigned char* mask = (const unsigned char*)d_in[2]; // (B, 512) bool
    const float* prior   = (const float*)d_in[3];   // (B, 512, 2048)
    const float* kw1 = (const float*)d_in[4];
    const float* kb1 = (const float*)d_in[5];
    const float* kw2 = (const float*)d_in[6];
    const float* kb2 = (const float*)d_in[7];
    const float* qw1 = (const float*)d_in[8];
    const float* qb1 = (const float*)d_in[9];
    const float* qw2 = (const float*)d_in[10];
    const float* qb2 = (const float*)d_in[11];
    const float* qw3 = (const float*)d_in[12];
    const float* qb3 = (const float*)d_in[13];

    ushort* us   = (ushort*)d_ws;
    ushort* kp   = us;
    ushort* h1   = kp  + KP_SZ;
    ushort* ke   = h1  + H1_SZ;
    ushort* qp   = ke  + KE_SZ;
    ushort* qh1  = qp  + QP_SZ;
    ushort* qh2  = qh1 + QH1_SZ;
    ushort* qe   = qh2 + QH2_SZ;
    ushort* w1t  = qe  + QE_SZ;
    ushort* w2t  = w1t + W1T_SZ;
    ushort* w3t  = w2t + W2T_SZ;
    ushort* w4t  = w3t + W3T_SZ;
    ushort* w5t  = w4t + W4T_SZ;
    ushort* lgp  = w5t + W5T_SZ;
    float*  k2   = (float*)(lgp + LGP_SZ);

    float* out_attn = (float*)d_out;
    float* out_lp   = out_attn + (size_t)NB * TT1 * TT2;

    // input prep
    prior_log_transpose<<<dim3(TT1 / 64, TT2 / 64, NB), 256, 0, stream>>>(prior, lgp);
    pad_keys_kernel<<<KP_SZ / 256, 256, 0, stream>>>(keys, kp);
    pad_transpose_queries_kernel<<<QP_SZ / 256, 256, 0, stream>>>(queries, qp);
    wtrans_kernel<<<(W1T_SZ + 255) / 256, 256, 0, stream>>>(kw1, w1t, 768, 768, 512);
    wtrans_kernel<<<(W2T_SZ + 255) / 256, 256, 0, stream>>>(kw2, w2t, 512, 512, 256);
    wtrans_kernel<<<(W3T_SZ + 255) / 256, 256, 0, stream>>>(qw1, w3t, 240, 256, 160);
    wtrans_kernel<<<(W4T_SZ + 255) / 256, 256, 0, stream>>>(qw2, w4t, 160, 160, 80);
    wtrans_kernel<<<(W5T_SZ + 255) / 256, 256, 0, stream>>>(qw3, w5t, 80, 96, 256);

    // key path
    mfma_gemm<768, 512, 1, 4, true><<<dim3(128, 8), 256, 0, stream>>>(
        kp, w1t, kb1, h1, 512, 514 * 256, 256);
    mfma_gemm<512, 256, 1, 4, false><<<dim3(128, 4), 256, 0, stream>>>(
        h1, w2t, kb2, ke, 512, 512 * 512, 512);
    k2_kernel<<<(NB * 512) / 4, 256, 0, stream>>>(ke, k2);

    // query path
    mfma_gemm<256, 160, 1, 10, true><<<dim3(512, 1), 256, 0, stream>>>(
        qp, w3t, qb1, qh1, 2048, 2050 * 80, 80);
    mfma_gemm<160, 80, 1, 5, true><<<dim3(512, 1), 256, 0, stream>>>(
        qh1, w4t, qb2, qh2, 2048, 2048 * 160, 160);
    mfma_gemm<96, 256, 1, 4, false><<<dim3(512, 4), 256, 0, stream>>>(
        qh2, w5t, qb3, qe, 2048, 2048 * 80, 80);

    // fused attention
    attn_kernel<<<NB * (TT1 / 16), 512, 0, stream>>>(
        qe, ke, k2, lgp, mask, out_attn, out_lp);
}

// Round 10
// 260.849 us; speedup vs baseline: 1.0199x; 1.0199x over previous
//
#include <hip/hip_runtime.h>
#include <cmath>

#define NB    16
#define TT1   2048
#define TT2   512
#define NATT  256
#define TEMP  0.0005f

// workspace element counts (ushort = bf16 unless noted)
#define KP_SZ   (NB*514*256)        // padded keys (B, 514, 256)
#define H1_SZ   (NB*512*512)        // key conv1 out (relu)
#define KE_SZ   (NB*512*256)        // key proj out
#define QP_SZ   (NB*2050*80)        // padded transposed queries
#define QH1_SZ  (NB*2048*160)
#define QH2_SZ  (NB*2048*80)
#define QE_SZ   (NB*2048*256)
#define W1T_SZ  (512*768)
#define W2T_SZ  (256*512)
#define W3T_SZ  (160*256)
#define W4T_SZ  (80*160)
#define W5T_SZ  (256*96)
#define LGP_SZ  (NB*TT1*TT2)        // bf16 log(prior+eps), transposed [b][t1][t2]
#define K2_SZ   (NB*512)            // f32

typedef __attribute__((ext_vector_type(8))) short short8v;
typedef __attribute__((ext_vector_type(4))) float f32x4;

__device__ inline ushort f2bf(float f) {
    unsigned int u = __float_as_uint(f);
    u += 0x7fff + ((u >> 16) & 1);      // RNE
    return (ushort)(u >> 16);
}
__device__ inline float bf2f(ushort u) {
    return __uint_as_float(((unsigned int)u) << 16);
}
__device__ inline void nts4(float* p, f32x4 v) {
    __builtin_nontemporal_store(v, (f32x4*)p);
}

// ---------------- padding / transpose (emit bf16) ----------------

__global__ void pad_keys_kernel(const float* __restrict__ keys, ushort* __restrict__ kp) {
    int idx = blockIdx.x * blockDim.x + threadIdx.x;
    if (idx >= KP_SZ) return;
    int c = idx & 255;
    int r = (idx >> 8) % 514;
    int b = idx / (514 * 256);
    float v = 0.f;
    if (r >= 1 && r <= 512)
        v = keys[((size_t)b * 512 + (r - 1)) * 256 + c];
    kp[idx] = f2bf(v);
}

__global__ void pad_transpose_queries_kernel(const float* __restrict__ q, ushort* __restrict__ qp) {
    int idx = blockIdx.x * blockDim.x + threadIdx.x;
    if (idx >= QP_SZ) return;
    int c = idx % 80;
    int r = (idx / 80) % 2050;
    int b = idx / (2050 * 80);
    float v = 0.f;
    if (r >= 1 && r <= 2048)
        v = q[((size_t)b * 80 + c) * 2048 + (r - 1)];
    qp[idx] = f2bf(v);
}

// ---------------- prior: transpose + log -> bf16 ----------------
// lgp[b][t1][t2] = bf16(log(prior[b][t2][t1] + 1e-8))
// nontemporal prior reads (read-once; keep L3 for lgp/qe/ke)

__global__ __launch_bounds__(256) void prior_log_transpose(
    const float* __restrict__ prior, ushort* __restrict__ lgp)
{
    __shared__ float T[64][65];
    const int b    = blockIdx.z;
    const int t1_0 = blockIdx.x * 64;
    const int t2_0 = blockIdx.y * 64;
    const int j  = threadIdx.x & 63;
    const int i0 = (threadIdx.x >> 6) * 16;
    #pragma unroll
    for (int r = 0; r < 16; ++r)
        T[i0 + r][j] = __builtin_nontemporal_load(
            prior + ((size_t)b * TT2 + t2_0 + i0 + r) * TT1 + t1_0 + j);
    __syncthreads();
    #pragma unroll
    for (int r = 0; r < 16; ++r) {
        const int p = i0 + r;
        const float v = T[j][p];
        lgp[((size_t)b * TT1 + t1_0 + p) * TT2 + t2_0 + j] = f2bf(__logf(v + 1e-8f));
    }
}

// ---------------- weight transpose + bf16 (+ K zero-pad) ----------------

__global__ void wtrans_kernel(const float* __restrict__ w, ushort* __restrict__ wt,
                              int Kreal, int Kpad, int N) {
    int idx = blockIdx.x * blockDim.x + threadIdx.x;
    if (idx >= N * Kpad) return;
    int k = idx % Kpad;
    int n = idx / Kpad;
    wt[idx] = (k < Kreal) ? f2bf(w[(size_t)k * N + n]) : (ushort)0;
}

// ---------------- bf16 MFMA conv-as-GEMM (MFRAG=2 best config) ----------------

template<int KPAD, int N, int MFRAG, int NFRAG, bool RELU>
__global__ __launch_bounds__(256) void mfma_gemm(
    const ushort* __restrict__ A, const ushort* __restrict__ Wt,
    const float* __restrict__ bias, ushort* __restrict__ C,
    int Tdim, int bStride, int rowStride)
{
    const int tid  = threadIdx.x;
    const int wv   = tid >> 6;
    const int lane = tid & 63;
    const int lr   = lane & 15;
    const int lk   = lane >> 4;
    const int m0   = blockIdx.x * (64 * MFRAG);
    const int n0   = blockIdx.y * (NFRAG * 16);

    const ushort* arow[MFRAG];
    #pragma unroll
    for (int mf = 0; mf < MFRAG; ++mf) {
        const int m = m0 + (wv * MFRAG + mf) * 16 + lr;
        arow[mf] = A + (size_t)(m / Tdim) * bStride
                     + (size_t)(m % Tdim) * rowStride + lk * 8;
    }
    const ushort* wtb = Wt + (size_t)(n0 + lr) * KPAD + lk * 8;

    f32x4 acc[MFRAG][NFRAG];
    #pragma unroll
    for (int mf = 0; mf < MFRAG; ++mf)
        #pragma unroll
        for (int f = 0; f < NFRAG; ++f) acc[mf][f] = (f32x4){0.f, 0.f, 0.f, 0.f};

    #pragma unroll
    for (int ks = 0; ks < KPAD / 32; ++ks) {
        short8v a[MFRAG];
        #pragma unroll
        for (int mf = 0; mf < MFRAG; ++mf)
            a[mf] = *(const short8v*)(arow[mf] + ks * 32);
        #pragma unroll
        for (int f = 0; f < NFRAG; ++f) {
            const short8v b = *(const short8v*)(wtb + (size_t)f * 16 * KPAD + ks * 32);
            #pragma unroll
            for (int mf = 0; mf < MFRAG; ++mf)
                acc[mf][f] = __builtin_amdgcn_mfma_f32_16x16x32_bf16(a[mf], b, acc[mf][f], 0, 0, 0);
        }
    }

    // C layout: col = lane&15 (N), row = (lane>>4)*4 + reg (M)
    #pragma unroll
    for (int mf = 0; mf < MFRAG; ++mf) {
        const int orow = m0 + (wv * MFRAG + mf) * 16 + lk * 4;
        #pragma unroll
        for (int f = 0; f < NFRAG; ++f) {
            const int col = n0 + f * 16 + lr;
            const float bv = bias[col];
            #pragma unroll
            for (int r = 0; r < 4; ++r) {
                float o = acc[mf][f][r] + bv;
                if (RELU) o = fmaxf(o, 0.f);
                C[(size_t)(orow + r) * N + col] = f2bf(o);
            }
        }
    }
}

// ---------------- k2t = -TEMP * sum(ke^2) (bf16 input) ----------------

__global__ void k2_kernel(const ushort* __restrict__ ke, float* __restrict__ k2) {
    int row = blockIdx.x * 4 + (threadIdx.x >> 6);   // (b*512 + t2)
    int lane = threadIdx.x & 63;
    ushort4 v = ((const ushort4*)(ke + (size_t)row * 256))[lane];
    float x = bf2f(v.x), y = bf2f(v.y), z = bf2f(v.z), w = bf2f(v.w);
    float ss = x * x + y * y + z * z + w * w;
    #pragma unroll
    for (int off = 32; off; off >>= 1) ss += __shfl_xor(ss, off);
    if (lane == 0) k2[row] = -TEMP * ss;
}

// ---------------- fused attention ----------------
// phase 1: wave w computes s = 2*TEMP*QK^T + k2t for cols [w*64, w*64+64) -> LDS S
// ONE barrier. phase 2: wave w owns rows 2w, 2w+1; lane covers t2 in [lane*8, lane*8+8);
// all reductions via in-wave shuffles; nontemporal output stores.

__device__ __forceinline__ void softmax_row(
    const float* __restrict__ Srow, const int e0,
    const short8v lgv, const unsigned long long mb,
    float* __restrict__ lprow, float* __restrict__ atrow)
{
    float s[8];
    *(float4*)&s[0] = *(const float4*)(Srow + e0);
    *(float4*)&s[4] = *(const float4*)(Srow + e0 + 4);

    // first softmax: logZ over full row
    float mx = fmaxf(fmaxf(fmaxf(s[0], s[1]), fmaxf(s[2], s[3])),
                     fmaxf(fmaxf(s[4], s[5]), fmaxf(s[6], s[7])));
    #pragma unroll
    for (int off = 32; off; off >>= 1) mx = fmaxf(mx, __shfl_xor(mx, off));
    float se = 0.f;
    #pragma unroll
    for (int j = 0; j < 8; ++j) se += __expf(s[j] - mx);
    #pragma unroll
    for (int off = 32; off; off >>= 1) se += __shfl_xor(se, off);
    const float logZ = mx + __logf(se);

    float uu[8], U[8];
    #pragma unroll
    for (int j = 0; j < 8; ++j) {
        uu[j] = s[j] + bf2f((ushort)lgv[j]);
        const bool msk = ((mb >> (8 * j)) & 0xffULL) != 0;
        U[j] = msk ? -INFINITY : uu[j];
    }
    nts4(lprow + e0,     (f32x4){uu[0] - logZ, uu[1] - logZ, uu[2] - logZ, uu[3] - logZ});
    nts4(lprow + e0 + 4, (f32x4){uu[4] - logZ, uu[5] - logZ, uu[6] - logZ, uu[7] - logZ});

    // masked softmax (exp values reused for output)
    float mx2 = fmaxf(fmaxf(fmaxf(U[0], U[1]), fmaxf(U[2], U[3])),
                      fmaxf(fmaxf(U[4], U[5]), fmaxf(U[6], U[7])));
    #pragma unroll
    for (int off = 32; off; off >>= 1) mx2 = fmaxf(mx2, __shfl_xor(mx2, off));
    float ex[8];
    float se2 = 0.f;
    #pragma unroll
    for (int j = 0; j < 8; ++j) { ex[j] = __expf(U[j] - mx2); se2 += ex[j]; }
    #pragma unroll
    for (int off = 32; off; off >>= 1) se2 += __shfl_xor(se2, off);
    const float inv = 1.0f / se2;
    nts4(atrow + e0,     (f32x4){ex[0] * inv, ex[1] * inv, ex[2] * inv, ex[3] * inv});
    nts4(atrow + e0 + 4, (f32x4){ex[4] * inv, ex[5] * inv, ex[6] * inv, ex[7] * inv});
}

__global__ __launch_bounds__(512) void attn_kernel(
    const ushort* __restrict__ qe, const ushort* __restrict__ ke,
    const float* __restrict__ k2t, const ushort* __restrict__ lgp,
    const unsigned char* __restrict__ mask,
    float* __restrict__ out_attn, float* __restrict__ out_lp)
{
    __shared__ float S[16][520];
    const int b    = blockIdx.x >> 7;
    const int t1_0 = (blockIdx.x & 127) << 4;
    const int tid  = threadIdx.x;
    const int lane = tid & 63;
    const int wv   = tid >> 6;

    // ---- prefetch for phase 2 (this wave's rows; consumed after barrier) ----
    const int e0 = lane << 3;                 // 8 t2 elems per lane
    const int r0 = wv << 1;
    const short8v lgv0 = *(const short8v*)(lgp + ((size_t)b * TT1 + t1_0 + r0) * TT2 + e0);
    const short8v lgv1 = *(const short8v*)(lgp + ((size_t)b * TT1 + t1_0 + r0 + 1) * TT2 + e0);
    const unsigned long long mb = *(const unsigned long long*)(mask + (size_t)b * TT2 + e0);

    // ---- phase 1: QK^T via MFMA, fold k2t ----
    {
        const int lr = lane & 15;
        const int lk = lane >> 4;
        const ushort* qrow = qe + ((size_t)b * TT1 + t1_0 + lr) * NATT + lk * 8;
        short8v a[8];
        #pragma unroll
        for (int k = 0; k < 8; ++k)
            a[k] = *(const short8v*)(qrow + k * 32);

        const ushort* kbase = ke + ((size_t)b * TT2 + wv * 64 + lr) * NATT + lk * 8;
        #pragma unroll
        for (int n = 0; n < 4; ++n) {
            f32x4 acc = {0.f, 0.f, 0.f, 0.f};
            const ushort* kb = kbase + (size_t)n * 16 * NATT;
            #pragma unroll
            for (int k = 0; k < 8; ++k) {
                short8v bfr = *(const short8v*)(kb + k * 32);
                acc = __builtin_amdgcn_mfma_f32_16x16x32_bf16(a[k], bfr, acc, 0, 0, 0);
            }
            const int col = wv * 64 + n * 16 + lr;
            const float k2v = k2t[(size_t)b * TT2 + col];
            #pragma unroll
            for (int r = 0; r < 4; ++r)
                S[lk * 4 + r][col] = fmaf(2.0f * TEMP, acc[r], k2v);
        }
    }
    __syncthreads();

    // ---- phase 2: per-wave rows, register-resident softmax pipeline ----
    float* lp0 = out_lp   + ((size_t)b * TT1 + t1_0 + r0) * TT2;
    float* at0 = out_attn + ((size_t)b * TT1 + t1_0 + r0) * TT2;
    softmax_row(&S[r0][0],     e0, lgv0, mb, lp0,       at0);
    softmax_row(&S[r0 + 1][0], e0, lgv1, mb, lp0 + TT2, at0 + TT2);
}

// ---------------- launch ----------------

extern "C" void kernel_launch(void* const* d_in, const int* in_sizes, int n_in,
                              void* d_out, int out_size, void* d_ws, size_t ws_size,
                              hipStream_t stream) {
    const float* queries = (const float*)d_in[0];   // (B, 80, 2048)
    const float* keys    = (const float*)d_in[1];   // (B, 512, 256)
    const unsigned char* mask = (const unsigned char*)d_in[2]; // (B, 512) bool
    const float* prior   = (const float*)d_in[3];   // (B, 512, 2048)
    const float* kw1 = (const float*)d_in[4];
    const float* kb1 = (const float*)d_in[5];
    const float* kw2 = (const float*)d_in[6];
    const float* kb2 = (const float*)d_in[7];
    const float* qw1 = (const float*)d_in[8];
    const float* qb1 = (const float*)d_in[9];
    const float* qw2 = (const float*)d_in[10];
    const float* qb2 = (const float*)d_in[11];
    const float* qw3 = (const float*)d_in[12];
    const float* qb3 = (const float*)d_in[13];

    ushort* us   = (ushort*)d_ws;
    ushort* kp   = us;
    ushort* h1   = kp  + KP_SZ;
    ushort* ke   = h1  + H1_SZ;
    ushort* qp   = ke  + KE_SZ;
    ushort* qh1  = qp  + QP_SZ;
    ushort* qh2  = qh1 + QH1_SZ;
    ushort* qe   = qh2 + QH2_SZ;
    ushort* w1t  = qe  + QE_SZ;
    ushort* w2t  = w1t + W1T_SZ;
    ushort* w3t  = w2t + W2T_SZ;
    ushort* w4t  = w3t + W3T_SZ;
    ushort* w5t  = w4t + W4T_SZ;
    ushort* lgp  = w5t + W5T_SZ;
    float*  k2   = (float*)(lgp + LGP_SZ);

    float* out_attn = (float*)d_out;
    float* out_lp   = out_attn + (size_t)NB * TT1 * TT2;

    // input prep (NO plt here — it runs right before attn for L3 locality)
    pad_keys_kernel<<<KP_SZ / 256, 256, 0, stream>>>(keys, kp);
    pad_transpose_queries_kernel<<<QP_SZ / 256, 256, 0, stream>>>(queries, qp);
    wtrans_kernel<<<(W1T_SZ + 255) / 256, 256, 0, stream>>>(kw1, w1t, 768, 768, 512);
    wtrans_kernel<<<(W2T_SZ + 255) / 256, 256, 0, stream>>>(kw2, w2t, 512, 512, 256);
    wtrans_kernel<<<(W3T_SZ + 255) / 256, 256, 0, stream>>>(qw1, w3t, 240, 256, 160);
    wtrans_kernel<<<(W4T_SZ + 255) / 256, 256, 0, stream>>>(qw2, w4t, 160, 160, 80);
    wtrans_kernel<<<(W5T_SZ + 255) / 256, 256, 0, stream>>>(qw3, w5t, 80, 96, 256);

    // key path (MFRAG=2, round-8 best config)
    mfma_gemm<768, 512, 2, 4, true><<<dim3(64, 8), 256, 0, stream>>>(
        kp, w1t, kb1, h1, 512, 514 * 256, 256);
    mfma_gemm<512, 256, 2, 4, false><<<dim3(64, 4), 256, 0, stream>>>(
        h1, w2t, kb2, ke, 512, 512 * 512, 512);
    k2_kernel<<<(NB * 512) / 4, 256, 0, stream>>>(ke, k2);

    // query path (MFRAG=2)
    mfma_gemm<256, 160, 2, 10, true><<<dim3(256, 1), 256, 0, stream>>>(
        qp, w3t, qb1, qh1, 2048, 2050 * 80, 80);
    mfma_gemm<160, 80, 2, 5, true><<<dim3(256, 1), 256, 0, stream>>>(
        qh1, w4t, qb2, qh2, 2048, 2048 * 160, 160);
    mfma_gemm<96, 256, 2, 4, false><<<dim3(256, 4), 256, 0, stream>>>(
        qh2, w5t, qb3, qe, 2048, 2048 * 80, 80);

    // prior prep LAST so lgp is L3-resident for attn
    prior_log_transpose<<<dim3(TT1 / 64, TT2 / 64, NB), 256, 0, stream>>>(prior, lgp);

    // fused attention
    attn_kernel<<<NB * (TT1 / 16), 512, 0, stream>>>(
        qe, ke, k2, lgp, mask, out_attn, out_lp);
}

// Round 11
// 243.634 us; speedup vs baseline: 1.0919x; 1.0707x over previous
//
#include <hip/hip_runtime.h>
#include <cmath>

#define NB    16
#define TT1   2048
#define TT2   512
#define NATT  256
#define TEMP  0.0005f

// workspace element counts (ushort = bf16 unless noted)
#define KP_SZ   (NB*514*256)        // padded keys (B, 514, 256)
#define KE_SZ   (NB*512*256)        // key proj out
#define QP_SZ   (NB*2050*80)        // padded transposed queries
#define QE_SZ   (NB*2048*256)
#define W1T_SZ  (512*768)
#define W2T_SZ  (256*512)
#define W3T_SZ  (160*256)
#define W4T_SZ  (80*160)
#define W5T_SZ  (256*96)
#define LGP_SZ  (NB*TT1*TT2)        // bf16 log(prior+eps), transposed [b][t1][t2]
#define K2_SZ   (NB*512)            // f32

typedef __attribute__((ext_vector_type(8))) short short8v;
typedef __attribute__((ext_vector_type(4))) float f32x4;

__device__ inline ushort f2bf(float f) {
    unsigned int u = __float_as_uint(f);
    u += 0x7fff + ((u >> 16) & 1);      // RNE
    return (ushort)(u >> 16);
}
__device__ inline float bf2f(ushort u) {
    return __uint_as_float(((unsigned int)u) << 16);
}

// ---------------- padding / transpose (emit bf16) ----------------

__global__ void pad_keys_kernel(const float* __restrict__ keys, ushort* __restrict__ kp) {
    int idx = blockIdx.x * blockDim.x + threadIdx.x;
    if (idx >= KP_SZ) return;
    int c = idx & 255;
    int r = (idx >> 8) % 514;
    int b = idx / (514 * 256);
    float v = 0.f;
    if (r >= 1 && r <= 512)
        v = keys[((size_t)b * 512 + (r - 1)) * 256 + c];
    kp[idx] = f2bf(v);
}

__global__ void pad_transpose_queries_kernel(const float* __restrict__ q, ushort* __restrict__ qp) {
    int idx = blockIdx.x * blockDim.x + threadIdx.x;
    if (idx >= QP_SZ) return;
    int c = idx % 80;
    int r = (idx / 80) % 2050;
    int b = idx / (2050 * 80);
    float v = 0.f;
    if (r >= 1 && r <= 2048)
        v = q[((size_t)b * 80 + c) * 2048 + (r - 1)];
    qp[idx] = f2bf(v);
}

// ---------------- prior: transpose + log -> bf16 ----------------

__global__ __launch_bounds__(256) void prior_log_transpose(
    const float* __restrict__ prior, ushort* __restrict__ lgp)
{
    __shared__ float T[64][65];
    const int b    = blockIdx.z;
    const int t1_0 = blockIdx.x * 64;
    const int t2_0 = blockIdx.y * 64;
    const int j  = threadIdx.x & 63;
    const int i0 = (threadIdx.x >> 6) * 16;
    #pragma unroll
    for (int r = 0; r < 16; ++r)
        T[i0 + r][j] = __builtin_nontemporal_load(
            prior + ((size_t)b * TT2 + t2_0 + i0 + r) * TT1 + t1_0 + j);
    __syncthreads();
    #pragma unroll
    for (int r = 0; r < 16; ++r) {
        const int p = i0 + r;
        const float v = T[j][p];
        lgp[((size_t)b * TT1 + t1_0 + p) * TT2 + t2_0 + j] = f2bf(__logf(v + 1e-8f));
    }
}

// ---------------- all weight transposes in one kernel ----------------

__global__ void wtrans_all(
    const float* __restrict__ kw1, const float* __restrict__ kw2,
    const float* __restrict__ qw1, const float* __restrict__ qw2,
    const float* __restrict__ qw3,
    ushort* __restrict__ w1t, ushort* __restrict__ w2t, ushort* __restrict__ w3t,
    ushort* __restrict__ w4t, ushort* __restrict__ w5t)
{
    int idx = blockIdx.x * blockDim.x + threadIdx.x;
    const float* w; ushort* wt; int Kreal, Kpad, N;
    if (idx < W1T_SZ) {
        w = kw1; wt = w1t; Kreal = 768; Kpad = 768; N = 512;
    } else if ((idx -= W1T_SZ) < W2T_SZ) {
        w = kw2; wt = w2t; Kreal = 512; Kpad = 512; N = 256;
    } else if ((idx -= W2T_SZ) < W3T_SZ) {
        w = qw1; wt = w3t; Kreal = 240; Kpad = 256; N = 160;
    } else if ((idx -= W3T_SZ) < W4T_SZ) {
        w = qw2; wt = w4t; Kreal = 160; Kpad = 160; N = 80;
    } else if ((idx -= W4T_SZ) < W5T_SZ) {
        w = qw3; wt = w5t; Kreal = 80; Kpad = 96; N = 256;
    } else return;
    int k = idx % Kpad;
    int n = idx / Kpad;
    wt[idx] = (k < Kreal) ? f2bf(w[(size_t)k * N + n]) : (ushort)0;
}

// ---------------- fused key path ----------------
// block: 256 thr (4 waves), 16 output rows (one t1.. t2-row tile: m = b*512 + t2).
// stage 1: h1 = relu(kp @ w1t + kb1) -> LDS [16][516]
// stage 2: ke = h1 @ w2t + kb2 -> global bf16; k2t = -TEMP*sum(ke^2) folded in.

__global__ __launch_bounds__(256) void fused_key(
    const ushort* __restrict__ kp, const ushort* __restrict__ w1t,
    const float* __restrict__ kb1, const ushort* __restrict__ w2t,
    const float* __restrict__ kb2, ushort* __restrict__ ke, float* __restrict__ k2)
{
    __shared__ ushort h1s[16][516];     // stride 1032B = 8 mod 128 -> 2-way only
    __shared__ float k2part[16][4];
    const int tid  = threadIdx.x;
    const int wv   = tid >> 6;
    const int lane = tid & 63;
    const int lr   = lane & 15;
    const int lk   = lane >> 4;
    const int m0   = blockIdx.x * 16;   // global row (b*512 + t2), 512%16==0

    // ---- stage 1: K=768, wave cols [wv*128, +128) ----
    {
        const int m = m0 + lr;
        const ushort* arow = kp + (size_t)(m / 512) * (514 * 256)
                                + (size_t)(m % 512) * 256 + lk * 8;
        const ushort* wtb = w1t + (size_t)(wv * 128 + lr) * 768 + lk * 8;
        f32x4 acc[8];
        #pragma unroll
        for (int f = 0; f < 8; ++f) acc[f] = (f32x4){0.f, 0.f, 0.f, 0.f};
        #pragma unroll
        for (int ks = 0; ks < 24; ++ks) {
            const short8v a = *(const short8v*)(arow + ks * 32);
            #pragma unroll
            for (int f = 0; f < 8; ++f) {
                const short8v b = *(const short8v*)(wtb + (size_t)f * 16 * 768 + ks * 32);
                acc[f] = __builtin_amdgcn_mfma_f32_16x16x32_bf16(a, b, acc[f], 0, 0, 0);
            }
        }
        #pragma unroll
        for (int f = 0; f < 8; ++f) {
            const int col = wv * 128 + f * 16 + lr;
            const float bv = kb1[col];
            #pragma unroll
            for (int r = 0; r < 4; ++r)
                h1s[lk * 4 + r][col] = f2bf(fmaxf(acc[f][r] + bv, 0.f));
        }
    }
    __syncthreads();

    // ---- stage 2: K=512 from LDS, wave cols [wv*64, +64) ----
    {
        f32x4 acc[4];
        #pragma unroll
        for (int f = 0; f < 4; ++f) acc[f] = (f32x4){0.f, 0.f, 0.f, 0.f};
        #pragma unroll
        for (int ks = 0; ks < 16; ++ks) {
            const short8v a = *(const short8v*)&h1s[lr][lk * 8 + ks * 32];
            #pragma unroll
            for (int f = 0; f < 4; ++f) {
                const short8v b = *(const short8v*)(w2t + (size_t)(wv * 64 + f * 16 + lr) * 512
                                                        + lk * 8 + ks * 32);
                acc[f] = __builtin_amdgcn_mfma_f32_16x16x32_bf16(a, b, acc[f], 0, 0, 0);
            }
        }
        float ss[4] = {0.f, 0.f, 0.f, 0.f};
        #pragma unroll
        for (int f = 0; f < 4; ++f) {
            const int col = wv * 64 + f * 16 + lr;
            const float bv = kb2[col];
            #pragma unroll
            for (int r = 0; r < 4; ++r) {
                const float o = acc[f][r] + bv;
                ke[(size_t)(m0 + lk * 4 + r) * 256 + col] = f2bf(o);
                ss[r] += o * o;
            }
        }
        #pragma unroll
        for (int r = 0; r < 4; ++r) {
            #pragma unroll
            for (int off = 1; off < 16; off <<= 1)
                ss[r] += __shfl_xor(ss[r], off);
        }
        if (lr == 0) {
            #pragma unroll
            for (int r = 0; r < 4; ++r) k2part[lk * 4 + r][wv] = ss[r];
        }
    }
    __syncthreads();
    if (tid < 16)
        k2[m0 + tid] = -TEMP * (k2part[tid][0] + k2part[tid][1] +
                                k2part[tid][2] + k2part[tid][3]);
}

// ---------------- fused query path ----------------
// block: 256 thr (4 waves), 64 output rows; wave owns rows [wv*16, +16).
// q1(K=256pad,N=160)+relu -> LDS s1 ; q2(K=160,N=80)+relu -> LDS s2 ; q3(K=96pad,N=256) -> qe

__global__ __launch_bounds__(256) void fused_query(
    const ushort* __restrict__ qp, const ushort* __restrict__ w3t,
    const float* __restrict__ qb1, const ushort* __restrict__ w4t,
    const float* __restrict__ qb2, const ushort* __restrict__ w5t,
    const float* __restrict__ qb3, ushort* __restrict__ qe)
{
    __shared__ ushort s1[64][164];      // stride 328B = 72 mod 128 -> 2-way only
    __shared__ ushort s2[64][100];      // stride 200B = 72 mod 128 -> 2-way only
    const int tid  = threadIdx.x;
    const int wv   = tid >> 6;
    const int lane = tid & 63;
    const int lr   = lane & 15;
    const int lk   = lane >> 4;
    const int m0   = blockIdx.x * 64;   // 2048%64==0 -> block within one batch

    // zero s2 pad cols [80,96) (read by stage 3 with zero weights on both sides)
    #pragma unroll
    for (int i = 0; i < 4; ++i) {
        const int e = tid * 4 + i;
        s2[e >> 4][80 + (e & 15)] = 0;
    }

    // ---- stage 1: q1, A from global qp (K contiguous over 3 rows x 80ch) ----
    {
        const int m = m0 + wv * 16 + lr;
        const ushort* arow = qp + (size_t)(m / 2048) * (2050 * 80)
                                + (size_t)(m % 2048) * 80 + lk * 8;
        f32x4 acc[10];
        #pragma unroll
        for (int f = 0; f < 10; ++f) acc[f] = (f32x4){0.f, 0.f, 0.f, 0.f};
        #pragma unroll
        for (int ks = 0; ks < 8; ++ks) {
            const short8v a = *(const short8v*)(arow + ks * 32);
            #pragma unroll
            for (int f = 0; f < 10; ++f) {
                const short8v b = *(const short8v*)(w3t + (size_t)(f * 16 + lr) * 256
                                                        + lk * 8 + ks * 32);
                acc[f] = __builtin_amdgcn_mfma_f32_16x16x32_bf16(a, b, acc[f], 0, 0, 0);
            }
        }
        #pragma unroll
        for (int f = 0; f < 10; ++f) {
            const int col = f * 16 + lr;
            const float bv = qb1[col];
            #pragma unroll
            for (int r = 0; r < 4; ++r)
                s1[wv * 16 + lk * 4 + r][col] = f2bf(fmaxf(acc[f][r] + bv, 0.f));
        }
    }
    __syncthreads();

    // ---- stage 2: q2, K=160 from s1 ----
    {
        f32x4 acc[5];
        #pragma unroll
        for (int f = 0; f < 5; ++f) acc[f] = (f32x4){0.f, 0.f, 0.f, 0.f};
        #pragma unroll
        for (int ks = 0; ks < 5; ++ks) {
            const short8v a = *(const short8v*)&s1[wv * 16 + lr][lk * 8 + ks * 32];
            #pragma unroll
            for (int f = 0; f < 5; ++f) {
                const short8v b = *(const short8v*)(w4t + (size_t)(f * 16 + lr) * 160
                                                        + lk * 8 + ks * 32);
                acc[f] = __builtin_amdgcn_mfma_f32_16x16x32_bf16(a, b, acc[f], 0, 0, 0);
            }
        }
        #pragma unroll
        for (int f = 0; f < 5; ++f) {
            const int col = f * 16 + lr;
            const float bv = qb2[col];
            #pragma unroll
            for (int r = 0; r < 4; ++r)
                s2[wv * 16 + lk * 4 + r][col] = f2bf(fmaxf(acc[f][r] + bv, 0.f));
        }
    }
    __syncthreads();

    // ---- stage 3: q3, K=96 (pad zeroed) from s2 -> qe ----
    {
        f32x4 acc[16];
        #pragma unroll
        for (int f = 0; f < 16; ++f) acc[f] = (f32x4){0.f, 0.f, 0.f, 0.f};
        #pragma unroll
        for (int ks = 0; ks < 3; ++ks) {
            const short8v a = *(const short8v*)&s2[wv * 16 + lr][lk * 8 + ks * 32];
            #pragma unroll
            for (int f = 0; f < 16; ++f) {
                const short8v b = *(const short8v*)(w5t + (size_t)(f * 16 + lr) * 96
                                                        + lk * 8 + ks * 32);
                acc[f] = __builtin_amdgcn_mfma_f32_16x16x32_bf16(a, b, acc[f], 0, 0, 0);
            }
        }
        #pragma unroll
        for (int f = 0; f < 16; ++f) {
            const int col = f * 16 + lr;
            const float bv = qb3[col];
            #pragma unroll
            for (int r = 0; r < 4; ++r)
                qe[(size_t)(m0 + wv * 16 + lk * 4 + r) * 256 + col] = f2bf(acc[f][r] + bv);
        }
    }
}

// ---------------- fused attention (round-8 verified, 91 us) ----------------

__global__ __launch_bounds__(512) void attn_kernel(
    const ushort* __restrict__ qe, const ushort* __restrict__ ke,
    const float* __restrict__ k2t, const ushort* __restrict__ lgp,
    const unsigned char* __restrict__ mask,
    float* __restrict__ out_attn, float* __restrict__ out_lp)
{
    __shared__ float S[16][516];
    __shared__ float rowZ[16];
    __shared__ float rowM[16];
    __shared__ float rowI[16];
    const int b    = blockIdx.x >> 7;
    const int t1_0 = (blockIdx.x & 127) << 4;
    const int tid  = threadIdx.x;
    const int lane = tid & 63;
    const int wv   = tid >> 6;
    const int t2   = tid;

    // ---- prefetch ----
    const bool mv = mask[(size_t)b * TT2 + t2] != 0;
    ushort lg[16];
    #pragma unroll
    for (int r = 0; r < 16; ++r)
        lg[r] = lgp[((size_t)b * TT1 + t1_0 + r) * TT2 + t2];

    // ---- phase 1: QK^T via MFMA, fold k2t ----
    {
        const int lr = lane & 15;
        const int lk = lane >> 4;
        const ushort* qrow = qe + ((size_t)b * TT1 + t1_0 + lr) * NATT + lk * 8;
        short8v a[8];
        #pragma unroll
        for (int k = 0; k < 8; ++k)
            a[k] = *(const short8v*)(qrow + k * 32);

        const ushort* kbase = ke + ((size_t)b * TT2 + wv * 64 + lr) * NATT + lk * 8;
        #pragma unroll
        for (int n = 0; n < 4; ++n) {
            f32x4 acc = {0.f, 0.f, 0.f, 0.f};
            const ushort* kb = kbase + (size_t)n * 16 * NATT;
            #pragma unroll
            for (int k = 0; k < 8; ++k) {
                short8v bfr = *(const short8v*)(kb + k * 32);
                acc = __builtin_amdgcn_mfma_f32_16x16x32_bf16(a[k], bfr, acc, 0, 0, 0);
            }
            const int col = wv * 64 + n * 16 + lr;
            const float k2v = k2t[(size_t)b * TT2 + col];
            #pragma unroll
            for (int r = 0; r < 4; ++r)
                S[lk * 4 + r][col] = fmaf(2.0f * TEMP, acc[r], k2v);
        }
    }
    __syncthreads();

    const int rr = tid >> 5;
    const int jj = tid & 31;

    // ---- phase 2a: logZ per row ----
    {
        float sv[16];
        #pragma unroll
        for (int k = 0; k < 16; ++k) sv[k] = S[rr][jj + 32 * k];
        float mx = sv[0];
        #pragma unroll
        for (int k = 1; k < 16; ++k) mx = fmaxf(mx, sv[k]);
        #pragma unroll
        for (int off = 16; off; off >>= 1) mx = fmaxf(mx, __shfl_xor(mx, off));
        float se = 0.f;
        #pragma unroll
        for (int k = 0; k < 16; ++k) se += __expf(sv[k] - mx);
        #pragma unroll
        for (int off = 16; off; off >>= 1) se += __shfl_xor(se, off);
        if (jj == 0) rowZ[rr] = mx + __logf(se);
    }
    __syncthreads();

    // ---- phase 2b: lp store, U (masked) -> LDS ----
    #pragma unroll
    for (int r = 0; r < 16; ++r) {
        const float uu = S[r][t2] + bf2f(lg[r]);
        out_lp[((size_t)b * TT1 + t1_0 + r) * TT2 + t2] = uu - rowZ[r];
        S[r][t2] = mv ? -INFINITY : uu;
    }
    __syncthreads();

    // ---- phase 2c: masked max + inv-sumexp per row ----
    {
        float uv[16];
        #pragma unroll
        for (int k = 0; k < 16; ++k) uv[k] = S[rr][jj + 32 * k];
        float mx = uv[0];
        #pragma unroll
        for (int k = 1; k < 16; ++k) mx = fmaxf(mx, uv[k]);
        #pragma unroll
        for (int off = 16; off; off >>= 1) mx = fmaxf(mx, __shfl_xor(mx, off));
        float se = 0.f;
        #pragma unroll
        for (int k = 0; k < 16; ++k) se += __expf(uv[k] - mx);
        #pragma unroll
        for (int off = 16; off; off >>= 1) se += __shfl_xor(se, off);
        if (jj == 0) { rowM[rr] = mx; rowI[rr] = 1.0f / se; }
    }
    __syncthreads();

    // ---- phase 2d: attn = exp(U - m2) * inv ----
    #pragma unroll
    for (int r = 0; r < 16; ++r) {
        const float a = __expf(S[r][t2] - rowM[r]) * rowI[r];
        out_attn[((size_t)b * TT1 + t1_0 + r) * TT2 + t2] = a;
    }
}

// ---------------- launch ----------------

extern "C" void kernel_launch(void* const* d_in, const int* in_sizes, int n_in,
                              void* d_out, int out_size, void* d_ws, size_t ws_size,
                              hipStream_t stream) {
    const float* queries = (const float*)d_in[0];   // (B, 80, 2048)
    const float* keys    = (const float*)d_in[1];   // (B, 512, 256)
    const unsigned char* mask = (const unsigned char*)d_in[2]; // (B, 512) bool
    const float* prior   = (const float*)d_in[3];   // (B, 512, 2048)
    const float* kw1 = (const float*)d_in[4];
    const float* kb1 = (const float*)d_in[5];
    const float* kw2 = (const float*)d_in[6];
    const float* kb2 = (const float*)d_in[7];
    const float* qw1 = (const float*)d_in[8];
    const float* qb1 = (const float*)d_in[9];
    const float* qw2 = (const float*)d_in[10];
    const float* qb2 = (const float*)d_in[11];
    const float* qw3 = (const float*)d_in[12];
    const float* qb3 = (const float*)d_in[13];

    ushort* us   = (ushort*)d_ws;
    ushort* kp   = us;
    ushort* ke   = kp  + KP_SZ;
    ushort* qp   = ke  + KE_SZ;
    ushort* qe   = qp  + QP_SZ;
    ushort* w1t  = qe  + QE_SZ;
    ushort* w2t  = w1t + W1T_SZ;
    ushort* w3t  = w2t + W2T_SZ;
    ushort* w4t  = w3t + W3T_SZ;
    ushort* w5t  = w4t + W4T_SZ;
    ushort* lgp  = w5t + W5T_SZ;
    float*  k2   = (float*)(lgp + LGP_SZ);

    float* out_attn = (float*)d_out;
    float* out_lp   = out_attn + (size_t)NB * TT1 * TT2;

    // input prep
    pad_keys_kernel<<<KP_SZ / 256, 256, 0, stream>>>(keys, kp);
    pad_transpose_queries_kernel<<<QP_SZ / 256, 256, 0, stream>>>(queries, qp);
    {
        const int wtot = W1T_SZ + W2T_SZ + W3T_SZ + W4T_SZ + W5T_SZ;
        wtrans_all<<<(wtot + 255) / 256, 256, 0, stream>>>(
            kw1, kw2, qw1, qw2, qw3, w1t, w2t, w3t, w4t, w5t);
    }

    // fused conv paths
    fused_key<<<(NB * 512) / 16, 256, 0, stream>>>(kp, w1t, kb1, w2t, kb2, ke, k2);
    fused_query<<<(NB * 2048) / 64, 256, 0, stream>>>(qp, w3t, qb1, w4t, qb2, w5t, qb3, qe);

    // prior prep
    prior_log_transpose<<<dim3(TT1 / 64, TT2 / 64, NB), 256, 0, stream>>>(prior, lgp);

    // fused attention
    attn_kernel<<<NB * (TT1 / 16), 512, 0, stream>>>(
        qe, ke, k2, lgp, mask, out_attn, out_lp);
}

// Round 12
// 217.751 us; speedup vs baseline: 1.2217x; 1.1189x over previous
//
#include <hip/hip_runtime.h>
#include <cmath>

#define NB    16
#define TT1   2048
#define TT2   512
#define NATT  256
#define TEMP  0.0005f

// workspace element counts (ushort = bf16 unless noted)
#define KP_SZ   (NB*514*256)        // padded keys (B, 514, 256)
#define KE_SZ   (NB*512*256)        // key proj out
#define QP_SZ   (NB*2050*80)        // padded transposed queries
#define QE_SZ   (NB*2048*256)
#define W1T_SZ  (512*768)
#define W2T_SZ  (256*512)
#define W3T_SZ  (160*256)
#define W4T_SZ  (80*160)
#define W5T_SZ  (256*96)
#define WTOT_SZ (W1T_SZ+W2T_SZ+W3T_SZ+W4T_SZ+W5T_SZ)
#define LGP_SZ  (NB*TT1*TT2)        // bf16 log(prior+eps), transposed [b][t1][t2]

// prep grid
#define PREP_PK_BLK   (KP_SZ/256)           // 8224
#define PREP_WT_BLK   (WTOT_SZ/256)         // 2354
#define PREP_QT_BLK   (NB*(TT1/64))         // 512
// mid grid
#define MID_PLT_BLK   ((TT1/64)*(TT2/64)*NB)  // 4096
#define MID_KEY_BLK   (NB*512/16)             // 512
#define MID_QRY_BLK   (NB*2048/64)            // 512

typedef __attribute__((ext_vector_type(8))) short short8v;
typedef __attribute__((ext_vector_type(4))) float f32x4;

__device__ inline ushort f2bf(float f) {
    unsigned int u = __float_as_uint(f);
    u += 0x7fff + ((u >> 16) & 1);      // RNE
    return (ushort)(u >> 16);
}
__device__ inline float bf2f(ushort u) {
    return __uint_as_float(((unsigned int)u) << 16);
}

// ==================== KERNEL 1: prep (pad_keys | wtrans | query transpose) ====================

__global__ __launch_bounds__(256) void prep_kernel(
    const float* __restrict__ keys, ushort* __restrict__ kp,
    const float* __restrict__ kw1, const float* __restrict__ kw2,
    const float* __restrict__ qw1, const float* __restrict__ qw2,
    const float* __restrict__ qw3,
    ushort* __restrict__ w1t, ushort* __restrict__ w2t, ushort* __restrict__ w3t,
    ushort* __restrict__ w4t, ushort* __restrict__ w5t,
    const float* __restrict__ queries, ushort* __restrict__ qp)
{
    __shared__ float T[80][65];
    const int bx  = blockIdx.x;
    const int tid = threadIdx.x;

    if (bx < PREP_PK_BLK) {
        // ---- pad keys -> bf16 ----
        const int idx = bx * 256 + tid;
        int c = idx & 255;
        int r = (idx >> 8) % 514;
        int b = idx / (514 * 256);
        float v = 0.f;
        if (r >= 1 && r <= 512)
            v = keys[((size_t)b * 512 + (r - 1)) * 256 + c];
        kp[idx] = f2bf(v);
        return;
    }
    if (bx < PREP_PK_BLK + PREP_WT_BLK) {
        // ---- weight transposes + bf16 (+K zero-pad) ----
        int idx = (bx - PREP_PK_BLK) * 256 + tid;
        const float* w; ushort* wt; int Kreal, Kpad, N;
        if (idx < W1T_SZ) {
            w = kw1; wt = w1t; Kreal = 768; Kpad = 768; N = 512;
        } else if ((idx -= W1T_SZ) < W2T_SZ) {
            w = kw2; wt = w2t; Kreal = 512; Kpad = 512; N = 256;
        } else if ((idx -= W2T_SZ) < W3T_SZ) {
            w = qw1; wt = w3t; Kreal = 240; Kpad = 256; N = 160;
        } else if ((idx -= W3T_SZ) < W4T_SZ) {
            w = qw2; wt = w4t; Kreal = 160; Kpad = 160; N = 80;
        } else {
            idx -= W4T_SZ;
            w = qw3; wt = w5t; Kreal = 80; Kpad = 96; N = 256;
        }
        int k = idx % Kpad;
        int n = idx / Kpad;
        wt[idx] = (k < Kreal) ? f2bf(w[(size_t)k * N + n]) : (ushort)0;
        return;
    }
    // ---- query transpose (LDS-tiled, coalesced both sides) ----
    {
        const int l  = bx - PREP_PK_BLK - PREP_WT_BLK;   // [0, 512)
        const int b  = l >> 5;
        const int t0 = (l & 31) * 64;
        const int g  = tid >> 6;       // 4 groups
        const int j  = tid & 63;
        // read: 20 channel-rows per group, 64 t contiguous
        #pragma unroll
        for (int r = 0; r < 20; ++r) {
            const int c = g * 20 + r;
            T[c][j] = queries[((size_t)b * 80 + c) * 2048 + t0 + j];
        }
        __syncthreads();
        // write: thread -> t = t0 + tid/4, c0 = (tid&3)*20, 20 contiguous ch
        const int tt = tid >> 2;
        const int c0 = (tid & 3) * 20;
        ushort* qrow = qp + (size_t)b * (2050 * 80) + (size_t)(t0 + tt + 1) * 80 + c0;
        #pragma unroll
        for (int i4 = 0; i4 < 5; ++i4) {
            ushort4 st;
            st.x = f2bf(T[c0 + i4 * 4 + 0][tt]);
            st.y = f2bf(T[c0 + i4 * 4 + 1][tt]);
            st.z = f2bf(T[c0 + i4 * 4 + 2][tt]);
            st.w = f2bf(T[c0 + i4 * 4 + 3][tt]);
            *(ushort4*)(qrow + i4 * 4) = st;
        }
        // zero pad rows (t = -1 and t = 2048)
        if (t0 == 0 && tid < 80)
            qp[(size_t)b * (2050 * 80) + tid] = 0;
        if (t0 == 2048 - 64 && tid < 80)
            qp[(size_t)b * (2050 * 80) + (size_t)2049 * 80 + tid] = 0;
    }
}

// ==================== KERNEL 2: mid (plt | fused_key | fused_query) ====================

__global__ __launch_bounds__(256) void mid_kernel(
    const float* __restrict__ prior, ushort* __restrict__ lgp,
    const ushort* __restrict__ kp, const ushort* __restrict__ w1t,
    const float* __restrict__ kb1, const ushort* __restrict__ w2t,
    const float* __restrict__ kb2, ushort* __restrict__ ke, float* __restrict__ k2,
    const ushort* __restrict__ qp, const ushort* __restrict__ w3t,
    const float* __restrict__ qb1, const ushort* __restrict__ w4t,
    const float* __restrict__ qb2, const ushort* __restrict__ w5t,
    const float* __restrict__ qb3, ushort* __restrict__ qe)
{
    __shared__ __align__(16) unsigned char smem[33792];
    const int bx   = blockIdx.x;
    const int tid  = threadIdx.x;
    const int wv   = tid >> 6;
    const int lane = tid & 63;
    const int lr   = lane & 15;
    const int lk   = lane >> 4;

    if (bx < MID_PLT_BLK) {
        // ---- prior: transpose + log -> bf16 ----
        float (*T)[65] = (float(*)[65])smem;
        const int l    = bx;
        const int t1_0 = (l & 31) * 64;
        const int t2_0 = ((l >> 5) & 7) * 64;
        const int b    = l >> 8;
        const int j  = tid & 63;
        const int i0 = (tid >> 6) * 16;
        #pragma unroll
        for (int r = 0; r < 16; ++r)
            T[i0 + r][j] = __builtin_nontemporal_load(
                prior + ((size_t)b * TT2 + t2_0 + i0 + r) * TT1 + t1_0 + j);
        __syncthreads();
        #pragma unroll
        for (int r = 0; r < 16; ++r) {
            const int p = i0 + r;
            const float v = T[j][p];
            lgp[((size_t)b * TT1 + t1_0 + p) * TT2 + t2_0 + j] = f2bf(__logf(v + 1e-8f));
        }
        return;
    }
    if (bx < MID_PLT_BLK + MID_KEY_BLK) {
        // ---- fused key path ----
        ushort (*h1s)[516] = (ushort(*)[516])smem;
        float (*k2part)[4] = (float(*)[4])(smem + 16 * 516 * 2);
        const int m0 = (bx - MID_PLT_BLK) * 16;

        // stage 1: K=768, wave cols [wv*128, +128)
        {
            const int m = m0 + lr;
            const ushort* arow = kp + (size_t)(m / 512) * (514 * 256)
                                    + (size_t)(m % 512) * 256 + lk * 8;
            const ushort* wtb = w1t + (size_t)(wv * 128 + lr) * 768 + lk * 8;
            f32x4 acc[8];
            #pragma unroll
            for (int f = 0; f < 8; ++f) acc[f] = (f32x4){0.f, 0.f, 0.f, 0.f};
            #pragma unroll
            for (int ks = 0; ks < 24; ++ks) {
                const short8v a = *(const short8v*)(arow + ks * 32);
                #pragma unroll
                for (int f = 0; f < 8; ++f) {
                    const short8v b = *(const short8v*)(wtb + (size_t)f * 16 * 768 + ks * 32);
                    acc[f] = __builtin_amdgcn_mfma_f32_16x16x32_bf16(a, b, acc[f], 0, 0, 0);
                }
            }
            #pragma unroll
            for (int f = 0; f < 8; ++f) {
                const int col = wv * 128 + f * 16 + lr;
                const float bv = kb1[col];
                #pragma unroll
                for (int r = 0; r < 4; ++r)
                    h1s[lk * 4 + r][col] = f2bf(fmaxf(acc[f][r] + bv, 0.f));
            }
        }
        __syncthreads();

        // stage 2: K=512 from LDS, wave cols [wv*64, +64); k2 folded
        {
            f32x4 acc[4];
            #pragma unroll
            for (int f = 0; f < 4; ++f) acc[f] = (f32x4){0.f, 0.f, 0.f, 0.f};
            #pragma unroll
            for (int ks = 0; ks < 16; ++ks) {
                const short8v a = *(const short8v*)&h1s[lr][lk * 8 + ks * 32];
                #pragma unroll
                for (int f = 0; f < 4; ++f) {
                    const short8v b = *(const short8v*)(w2t + (size_t)(wv * 64 + f * 16 + lr) * 512
                                                            + lk * 8 + ks * 32);
                    acc[f] = __builtin_amdgcn_mfma_f32_16x16x32_bf16(a, b, acc[f], 0, 0, 0);
                }
            }
            float ss[4] = {0.f, 0.f, 0.f, 0.f};
            #pragma unroll
            for (int f = 0; f < 4; ++f) {
                const int col = wv * 64 + f * 16 + lr;
                const float bv = kb2[col];
                #pragma unroll
                for (int r = 0; r < 4; ++r) {
                    const float o = acc[f][r] + bv;
                    ke[(size_t)(m0 + lk * 4 + r) * 256 + col] = f2bf(o);
                    ss[r] += o * o;
                }
            }
            #pragma unroll
            for (int r = 0; r < 4; ++r) {
                #pragma unroll
                for (int off = 1; off < 16; off <<= 1)
                    ss[r] += __shfl_xor(ss[r], off);
            }
            if (lr == 0) {
                #pragma unroll
                for (int r = 0; r < 4; ++r) k2part[lk * 4 + r][wv] = ss[r];
            }
        }
        __syncthreads();
        if (tid < 16)
            k2[m0 + tid] = -TEMP * (k2part[tid][0] + k2part[tid][1] +
                                    k2part[tid][2] + k2part[tid][3]);
        return;
    }
    // ---- fused query path ----
    {
        ushort (*s1)[164] = (ushort(*)[164])smem;
        ushort (*s2)[100] = (ushort(*)[100])(smem + 64 * 164 * 2);
        const int m0 = (bx - MID_PLT_BLK - MID_KEY_BLK) * 64;

        // zero s2 pad cols [80,96)
        #pragma unroll
        for (int i = 0; i < 4; ++i) {
            const int e = tid * 4 + i;
            s2[e >> 4][80 + (e & 15)] = 0;
        }

        // stage 1: q1 (K=256pad, N=160) + relu -> s1
        {
            const int m = m0 + wv * 16 + lr;
            const ushort* arow = qp + (size_t)(m / 2048) * (2050 * 80)
                                    + (size_t)(m % 2048) * 80 + lk * 8;
            f32x4 acc[10];
            #pragma unroll
            for (int f = 0; f < 10; ++f) acc[f] = (f32x4){0.f, 0.f, 0.f, 0.f};
            #pragma unroll
            for (int ks = 0; ks < 8; ++ks) {
                const short8v a = *(const short8v*)(arow + ks * 32);
                #pragma unroll
                for (int f = 0; f < 10; ++f) {
                    const short8v b = *(const short8v*)(w3t + (size_t)(f * 16 + lr) * 256
                                                            + lk * 8 + ks * 32);
                    acc[f] = __builtin_amdgcn_mfma_f32_16x16x32_bf16(a, b, acc[f], 0, 0, 0);
                }
            }
            #pragma unroll
            for (int f = 0; f < 10; ++f) {
                const int col = f * 16 + lr;
                const float bv = qb1[col];
                #pragma unroll
                for (int r = 0; r < 4; ++r)
                    s1[wv * 16 + lk * 4 + r][col] = f2bf(fmaxf(acc[f][r] + bv, 0.f));
            }
        }
        __syncthreads();

        // stage 2: q2 (K=160, N=80) + relu -> s2
        {
            f32x4 acc[5];
            #pragma unroll
            for (int f = 0; f < 5; ++f) acc[f] = (f32x4){0.f, 0.f, 0.f, 0.f};
            #pragma unroll
            for (int ks = 0; ks < 5; ++ks) {
                const short8v a = *(const short8v*)&s1[wv * 16 + lr][lk * 8 + ks * 32];
                #pragma unroll
                for (int f = 0; f < 5; ++f) {
                    const short8v b = *(const short8v*)(w4t + (size_t)(f * 16 + lr) * 160
                                                            + lk * 8 + ks * 32);
                    acc[f] = __builtin_amdgcn_mfma_f32_16x16x32_bf16(a, b, acc[f], 0, 0, 0);
                }
            }
            #pragma unroll
            for (int f = 0; f < 5; ++f) {
                const int col = f * 16 + lr;
                const float bv = qb2[col];
                #pragma unroll
                for (int r = 0; r < 4; ++r)
                    s2[wv * 16 + lk * 4 + r][col] = f2bf(fmaxf(acc[f][r] + bv, 0.f));
            }
        }
        __syncthreads();

        // stage 3: q3 (K=96 pad) -> qe
        {
            f32x4 acc[16];
            #pragma unroll
            for (int f = 0; f < 16; ++f) acc[f] = (f32x4){0.f, 0.f, 0.f, 0.f};
            #pragma unroll
            for (int ks = 0; ks < 3; ++ks) {
                const short8v a = *(const short8v*)&s2[wv * 16 + lr][lk * 8 + ks * 32];
                #pragma unroll
                for (int f = 0; f < 16; ++f) {
                    const short8v b = *(const short8v*)(w5t + (size_t)(f * 16 + lr) * 96
                                                            + lk * 8 + ks * 32);
                    acc[f] = __builtin_amdgcn_mfma_f32_16x16x32_bf16(a, b, acc[f], 0, 0, 0);
                }
            }
            #pragma unroll
            for (int f = 0; f < 16; ++f) {
                const int col = f * 16 + lr;
                const float bv = qb3[col];
                #pragma unroll
                for (int r = 0; r < 4; ++r)
                    qe[(size_t)(m0 + wv * 16 + lk * 4 + r) * 256 + col] = f2bf(acc[f][r] + bv);
            }
        }
    }
}

// ==================== KERNEL 3: fused attention (round-8 verified, 91 us) ====================

__global__ __launch_bounds__(512) void attn_kernel(
    const ushort* __restrict__ qe, const ushort* __restrict__ ke,
    const float* __restrict__ k2t, const ushort* __restrict__ lgp,
    const unsigned char* __restrict__ mask,
    float* __restrict__ out_attn, float* __restrict__ out_lp)
{
    __shared__ float S[16][516];
    __shared__ float rowZ[16];
    __shared__ float rowM[16];
    __shared__ float rowI[16];
    const int b    = blockIdx.x >> 7;
    const int t1_0 = (blockIdx.x & 127) << 4;
    const int tid  = threadIdx.x;
    const int lane = tid & 63;
    const int wv   = tid >> 6;
    const int t2   = tid;

    // ---- prefetch ----
    const bool mv = mask[(size_t)b * TT2 + t2] != 0;
    ushort lg[16];
    #pragma unroll
    for (int r = 0; r < 16; ++r)
        lg[r] = lgp[((size_t)b * TT1 + t1_0 + r) * TT2 + t2];

    // ---- phase 1: QK^T via MFMA, fold k2t ----
    {
        const int lr = lane & 15;
        const int lk = lane >> 4;
        const ushort* qrow = qe + ((size_t)b * TT1 + t1_0 + lr) * NATT + lk * 8;
        short8v a[8];
        #pragma unroll
        for (int k = 0; k < 8; ++k)
            a[k] = *(const short8v*)(qrow + k * 32);

        const ushort* kbase = ke + ((size_t)b * TT2 + wv * 64 + lr) * NATT + lk * 8;
        #pragma unroll
        for (int n = 0; n < 4; ++n) {
            f32x4 acc = {0.f, 0.f, 0.f, 0.f};
            const ushort* kb = kbase + (size_t)n * 16 * NATT;
            #pragma unroll
            for (int k = 0; k < 8; ++k) {
                short8v bfr = *(const short8v*)(kb + k * 32);
                acc = __builtin_amdgcn_mfma_f32_16x16x32_bf16(a[k], bfr, acc, 0, 0, 0);
            }
            const int col = wv * 64 + n * 16 + lr;
            const float k2v = k2t[(size_t)b * TT2 + col];
            #pragma unroll
            for (int r = 0; r < 4; ++r)
                S[lk * 4 + r][col] = fmaf(2.0f * TEMP, acc[r], k2v);
        }
    }
    __syncthreads();

    const int rr = tid >> 5;
    const int jj = tid & 31;

    // ---- phase 2a: logZ per row ----
    {
        float sv[16];
        #pragma unroll
        for (int k = 0; k < 16; ++k) sv[k] = S[rr][jj + 32 * k];
        float mx = sv[0];
        #pragma unroll
        for (int k = 1; k < 16; ++k) mx = fmaxf(mx, sv[k]);
        #pragma unroll
        for (int off = 16; off; off >>= 1) mx = fmaxf(mx, __shfl_xor(mx, off));
        float se = 0.f;
        #pragma unroll
        for (int k = 0; k < 16; ++k) se += __expf(sv[k] - mx);
        #pragma unroll
        for (int off = 16; off; off >>= 1) se += __shfl_xor(se, off);
        if (jj == 0) rowZ[rr] = mx + __logf(se);
    }
    __syncthreads();

    // ---- phase 2b: lp store, U (masked) -> LDS ----
    #pragma unroll
    for (int r = 0; r < 16; ++r) {
        const float uu = S[r][t2] + bf2f(lg[r]);
        out_lp[((size_t)b * TT1 + t1_0 + r) * TT2 + t2] = uu - rowZ[r];
        S[r][t2] = mv ? -INFINITY : uu;
    }
    __syncthreads();

    // ---- phase 2c: masked max + inv-sumexp per row ----
    {
        float uv[16];
        #pragma unroll
        for (int k = 0; k < 16; ++k) uv[k] = S[rr][jj + 32 * k];
        float mx = uv[0];
        #pragma unroll
        for (int k = 1; k < 16; ++k) mx = fmaxf(mx, uv[k]);
        #pragma unroll
        for (int off = 16; off; off >>= 1) mx = fmaxf(mx, __shfl_xor(mx, off));
        float se = 0.f;
        #pragma unroll
        for (int k = 0; k < 16; ++k) se += __expf(uv[k] - mx);
        #pragma unroll
        for (int off = 16; off; off >>= 1) se += __shfl_xor(se, off);
        if (jj == 0) { rowM[rr] = mx; rowI[rr] = 1.0f / se; }
    }
    __syncthreads();

    // ---- phase 2d: attn = exp(U - m2) * inv ----
    #pragma unroll
    for (int r = 0; r < 16; ++r) {
        const float a = __expf(S[r][t2] - rowM[r]) * rowI[r];
        out_attn[((size_t)b * TT1 + t1_0 + r) * TT2 + t2] = a;
    }
}

// ---------------- launch ----------------

extern "C" void kernel_launch(void* const* d_in, const int* in_sizes, int n_in,
                              void* d_out, int out_size, void* d_ws, size_t ws_size,
                              hipStream_t stream) {
    const float* queries = (const float*)d_in[0];   // (B, 80, 2048)
    const float* keys    = (const float*)d_in[1];   // (B, 512, 256)
    const unsigned char* mask = (const unsigned char*)d_in[2]; // (B, 512) bool
    const float* prior   = (const float*)d_in[3];   // (B, 512, 2048)
    const float* kw1 = (const float*)d_in[4];
    const float* kb1 = (const float*)d_in[5];
    const float* kw2 = (const float*)d_in[6];
    const float* kb2 = (const float*)d_in[7];
    const float* qw1 = (const float*)d_in[8];
    const float* qb1 = (const float*)d_in[9];
    const float* qw2 = (const float*)d_in[10];
    const float* qb2 = (const float*)d_in[11];
    const float* qw3 = (const float*)d_in[12];
    const float* qb3 = (const float*)d_in[13];

    ushort* us   = (ushort*)d_ws;
    ushort* kp   = us;
    ushort* ke   = kp  + KP_SZ;
    ushort* qp   = ke  + KE_SZ;
    ushort* qe   = qp  + QP_SZ;
    ushort* w1t  = qe  + QE_SZ;
    ushort* w2t  = w1t + W1T_SZ;
    ushort* w3t  = w2t + W2T_SZ;
    ushort* w4t  = w3t + W3T_SZ;
    ushort* w5t  = w4t + W4T_SZ;
    ushort* lgp  = w5t + W5T_SZ;
    float*  k2   = (float*)(lgp + LGP_SZ);

    float* out_attn = (float*)d_out;
    float* out_lp   = out_attn + (size_t)NB * TT1 * TT2;

    prep_kernel<<<PREP_PK_BLK + PREP_WT_BLK + PREP_QT_BLK, 256, 0, stream>>>(
        keys, kp, kw1, kw2, qw1, qw2, qw3, w1t, w2t, w3t, w4t, w5t, queries, qp);

    mid_kernel<<<MID_PLT_BLK + MID_KEY_BLK + MID_QRY_BLK, 256, 0, stream>>>(
        prior, lgp, kp, w1t, kb1, w2t, kb2, ke, k2,
        qp, w3t, qb1, w4t, qb2, w5t, qb3, qe);

    attn_kernel<<<NB * (TT1 / 16), 512, 0, stream>>>(
        qe, ke, k2, lgp, mask, out_attn, out_lp);
}

// Round 13
// 217.580 us; speedup vs baseline: 1.2227x; 1.0008x over previous
//
#include <hip/hip_runtime.h>
#include <cmath>

#define NB    16
#define TT1   2048
#define TT2   512
#define NATT  256
#define TEMP  0.0005f

// workspace element counts (ushort = bf16 unless noted)
#define KP_SZ   (NB*514*256)        // padded keys (B, 514, 256)
#define KE_SZ   (NB*512*256)        // key proj out
#define QP_SZ   (NB*2050*80)        // padded transposed queries
#define QE_SZ   (NB*2048*256)
#define W1T_SZ  (512*768)
#define W2T_SZ  (256*512)
#define W3T_SZ  (160*256)
#define W4T_SZ  (80*160)
#define W5T_SZ  (256*96)
#define WTOT_SZ (W1T_SZ+W2T_SZ+W3T_SZ+W4T_SZ+W5T_SZ)
#define LGP_SZ  (NB*TT1*TT2)        // bf16 log(prior+eps), transposed [b][t1][t2]

// prep grid
#define PREP_PK_BLK   (KP_SZ/256)           // 8224
#define PREP_WT_BLK   (WTOT_SZ/256)         // 2354
#define PREP_QT_BLK   (NB*(TT1/64))         // 512
// conv grid
#define CONV_KEY_BLK  (NB*512/16)           // 512
#define CONV_QRY_BLK  (NB*2048/64)          // 512

typedef __attribute__((ext_vector_type(8))) short short8v;
typedef __attribute__((ext_vector_type(4))) float f32x4;

__device__ inline ushort f2bf(float f) {
    unsigned int u = __float_as_uint(f);
    u += 0x7fff + ((u >> 16) & 1);      // RNE
    return (ushort)(u >> 16);
}
__device__ inline float bf2f(ushort u) {
    return __uint_as_float(((unsigned int)u) << 16);
}

// ==================== KERNEL 1: prep (pad_keys | wtrans | query transpose) ====================

__global__ __launch_bounds__(256) void prep_kernel(
    const float* __restrict__ keys, ushort* __restrict__ kp,
    const float* __restrict__ kw1, const float* __restrict__ kw2,
    const float* __restrict__ qw1, const float* __restrict__ qw2,
    const float* __restrict__ qw3,
    ushort* __restrict__ w1t, ushort* __restrict__ w2t, ushort* __restrict__ w3t,
    ushort* __restrict__ w4t, ushort* __restrict__ w5t,
    const float* __restrict__ queries, ushort* __restrict__ qp)
{
    __shared__ float T[80][65];
    const int bx  = blockIdx.x;
    const int tid = threadIdx.x;

    if (bx < PREP_PK_BLK) {
        const int idx = bx * 256 + tid;
        int c = idx & 255;
        int r = (idx >> 8) % 514;
        int b = idx / (514 * 256);
        float v = 0.f;
        if (r >= 1 && r <= 512)
            v = keys[((size_t)b * 512 + (r - 1)) * 256 + c];
        kp[idx] = f2bf(v);
        return;
    }
    if (bx < PREP_PK_BLK + PREP_WT_BLK) {
        int idx = (bx - PREP_PK_BLK) * 256 + tid;
        const float* w; ushort* wt; int Kreal, Kpad, N;
        if (idx < W1T_SZ) {
            w = kw1; wt = w1t; Kreal = 768; Kpad = 768; N = 512;
        } else if ((idx -= W1T_SZ) < W2T_SZ) {
            w = kw2; wt = w2t; Kreal = 512; Kpad = 512; N = 256;
        } else if ((idx -= W2T_SZ) < W3T_SZ) {
            w = qw1; wt = w3t; Kreal = 240; Kpad = 256; N = 160;
        } else if ((idx -= W3T_SZ) < W4T_SZ) {
            w = qw2; wt = w4t; Kreal = 160; Kpad = 160; N = 80;
        } else {
            idx -= W4T_SZ;
            w = qw3; wt = w5t; Kreal = 80; Kpad = 96; N = 256;
        }
        int k = idx % Kpad;
        int n = idx / Kpad;
        wt[idx] = (k < Kreal) ? f2bf(w[(size_t)k * N + n]) : (ushort)0;
        return;
    }
    // ---- query transpose (LDS-tiled) ----
    {
        const int l  = bx - PREP_PK_BLK - PREP_WT_BLK;   // [0, 512)
        const int b  = l >> 5;
        const int t0 = (l & 31) * 64;
        const int g  = tid >> 6;
        const int j  = tid & 63;
        #pragma unroll
        for (int r = 0; r < 20; ++r) {
            const int c = g * 20 + r;
            T[c][j] = queries[((size_t)b * 80 + c) * 2048 + t0 + j];
        }
        __syncthreads();
        const int tt = tid >> 2;
        const int c0 = (tid & 3) * 20;
        ushort* qrow = qp + (size_t)b * (2050 * 80) + (size_t)(t0 + tt + 1) * 80 + c0;
        #pragma unroll
        for (int i4 = 0; i4 < 5; ++i4) {
            ushort4 st;
            st.x = f2bf(T[c0 + i4 * 4 + 0][tt]);
            st.y = f2bf(T[c0 + i4 * 4 + 1][tt]);
            st.z = f2bf(T[c0 + i4 * 4 + 2][tt]);
            st.w = f2bf(T[c0 + i4 * 4 + 3][tt]);
            *(ushort4*)(qrow + i4 * 4) = st;
        }
        if (t0 == 0 && tid < 80)
            qp[(size_t)b * (2050 * 80) + tid] = 0;
        if (t0 == 2048 - 64 && tid < 80)
            qp[(size_t)b * (2050 * 80) + (size_t)2049 * 80 + tid] = 0;
    }
}

// ==================== KERNEL 2: conv (fused_key | fused_query), 8 waves/block ====================

__global__ __launch_bounds__(512) void conv_kernel(
    const ushort* __restrict__ kp, const ushort* __restrict__ w1t,
    const float* __restrict__ kb1, const ushort* __restrict__ w2t,
    const float* __restrict__ kb2, ushort* __restrict__ ke, float* __restrict__ k2,
    const ushort* __restrict__ qp, const ushort* __restrict__ w3t,
    const float* __restrict__ qb1, const ushort* __restrict__ w4t,
    const float* __restrict__ qb2, const ushort* __restrict__ w5t,
    const float* __restrict__ qb3, ushort* __restrict__ qe)
{
    __shared__ __align__(16) unsigned char smem[33792];
    const int bx   = blockIdx.x;
    const int tid  = threadIdx.x;
    const int wv   = tid >> 6;        // 0..7
    const int lane = tid & 63;
    const int lr   = lane & 15;
    const int lk   = lane >> 4;

    if (bx < CONV_KEY_BLK) {
        // ---- fused key path: 16 rows/block, 8 waves split cols ----
        ushort (*h1s)[516] = (ushort(*)[516])smem;
        float (*k2part)[8] = (float(*)[8])(smem + 16 * 516 * 2);
        const int m0 = bx * 16;

        // stage 1: K=768, N=512; wave w cols [w*64, +64)
        {
            const int m = m0 + lr;
            const ushort* arow = kp + (size_t)(m / 512) * (514 * 256)
                                    + (size_t)(m % 512) * 256 + lk * 8;
            const ushort* wtb = w1t + (size_t)(wv * 64 + lr) * 768 + lk * 8;
            f32x4 acc[4];
            #pragma unroll
            for (int f = 0; f < 4; ++f) acc[f] = (f32x4){0.f, 0.f, 0.f, 0.f};
            #pragma unroll
            for (int ks = 0; ks < 24; ++ks) {
                const short8v a = *(const short8v*)(arow + ks * 32);
                #pragma unroll
                for (int f = 0; f < 4; ++f) {
                    const short8v b = *(const short8v*)(wtb + (size_t)f * 16 * 768 + ks * 32);
                    acc[f] = __builtin_amdgcn_mfma_f32_16x16x32_bf16(a, b, acc[f], 0, 0, 0);
                }
            }
            #pragma unroll
            for (int f = 0; f < 4; ++f) {
                const int col = wv * 64 + f * 16 + lr;
                const float bv = kb1[col];
                #pragma unroll
                for (int r = 0; r < 4; ++r)
                    h1s[lk * 4 + r][col] = f2bf(fmaxf(acc[f][r] + bv, 0.f));
            }
        }
        __syncthreads();

        // stage 2: K=512 from LDS, N=256; wave w cols [w*32, +32); k2 folded
        {
            f32x4 acc[2];
            #pragma unroll
            for (int f = 0; f < 2; ++f) acc[f] = (f32x4){0.f, 0.f, 0.f, 0.f};
            #pragma unroll
            for (int ks = 0; ks < 16; ++ks) {
                const short8v a = *(const short8v*)&h1s[lr][lk * 8 + ks * 32];
                #pragma unroll
                for (int f = 0; f < 2; ++f) {
                    const short8v b = *(const short8v*)(w2t + (size_t)(wv * 32 + f * 16 + lr) * 512
                                                            + lk * 8 + ks * 32);
                    acc[f] = __builtin_amdgcn_mfma_f32_16x16x32_bf16(a, b, acc[f], 0, 0, 0);
                }
            }
            float ss[4] = {0.f, 0.f, 0.f, 0.f};
            #pragma unroll
            for (int f = 0; f < 2; ++f) {
                const int col = wv * 32 + f * 16 + lr;
                const float bv = kb2[col];
                #pragma unroll
                for (int r = 0; r < 4; ++r) {
                    const float o = acc[f][r] + bv;
                    ke[(size_t)(m0 + lk * 4 + r) * 256 + col] = f2bf(o);
                    ss[r] += o * o;
                }
            }
            #pragma unroll
            for (int r = 0; r < 4; ++r) {
                #pragma unroll
                for (int off = 1; off < 16; off <<= 1)
                    ss[r] += __shfl_xor(ss[r], off);
            }
            if (lr == 0) {
                #pragma unroll
                for (int r = 0; r < 4; ++r) k2part[lk * 4 + r][wv] = ss[r];
            }
        }
        __syncthreads();
        if (tid < 16) {
            float s = 0.f;
            #pragma unroll
            for (int w = 0; w < 8; ++w) s += k2part[tid][w];
            k2[m0 + tid] = -TEMP * s;
        }
        return;
    }
    // ---- fused query path: 64 rows/block, 4 row-groups x 2 col-groups ----
    {
        ushort (*s1)[164] = (ushort(*)[164])smem;
        ushort (*s2)[100] = (ushort(*)[100])(smem + 64 * 164 * 2);
        const int m0 = (bx - CONV_KEY_BLK) * 64;
        const int cg = wv >> 2;           // col group 0/1
        const int rb = (wv & 3) * 16;     // row base

        // zero s2 pad cols [80,96): 1024 entries over 512 threads
        #pragma unroll
        for (int i = 0; i < 2; ++i) {
            const int e = tid * 2 + i;
            s2[e >> 4][80 + (e & 15)] = 0;
        }

        // stage 1: q1 (K=256pad, N=160); col group cg covers frags cg*5..+5
        {
            const int m = m0 + rb + lr;
            const ushort* arow = qp + (size_t)(m / 2048) * (2050 * 80)
                                    + (size_t)(m % 2048) * 80 + lk * 8;
            f32x4 acc[5];
            #pragma unroll
            for (int f = 0; f < 5; ++f) acc[f] = (f32x4){0.f, 0.f, 0.f, 0.f};
            #pragma unroll
            for (int ks = 0; ks < 8; ++ks) {
                const short8v a = *(const short8v*)(arow + ks * 32);
                #pragma unroll
                for (int f = 0; f < 5; ++f) {
                    const int cf = cg * 5 + f;
                    const short8v b = *(const short8v*)(w3t + (size_t)(cf * 16 + lr) * 256
                                                            + lk * 8 + ks * 32);
                    acc[f] = __builtin_amdgcn_mfma_f32_16x16x32_bf16(a, b, acc[f], 0, 0, 0);
                }
            }
            #pragma unroll
            for (int f = 0; f < 5; ++f) {
                const int col = (cg * 5 + f) * 16 + lr;
                const float bv = qb1[col];
                #pragma unroll
                for (int r = 0; r < 4; ++r)
                    s1[rb + lk * 4 + r][col] = f2bf(fmaxf(acc[f][r] + bv, 0.f));
            }
        }
        __syncthreads();

        // stage 2: q2 (K=160, N=80 = 5 frags; cg0 -> 0..2, cg1 -> 3..4)
        {
            const int nf = cg ? 2 : 3;
            const int f0 = cg ? 3 : 0;
            f32x4 acc[3];
            #pragma unroll
            for (int f = 0; f < 3; ++f) acc[f] = (f32x4){0.f, 0.f, 0.f, 0.f};
            #pragma unroll
            for (int ks = 0; ks < 5; ++ks) {
                const short8v a = *(const short8v*)&s1[rb + lr][lk * 8 + ks * 32];
                for (int f = 0; f < nf; ++f) {
                    const int cf = f0 + f;
                    const short8v b = *(const short8v*)(w4t + (size_t)(cf * 16 + lr) * 160
                                                            + lk * 8 + ks * 32);
                    acc[f] = __builtin_amdgcn_mfma_f32_16x16x32_bf16(a, b, acc[f], 0, 0, 0);
                }
            }
            for (int f = 0; f < nf; ++f) {
                const int col = (f0 + f) * 16 + lr;
                const float bv = qb2[col];
                #pragma unroll
                for (int r = 0; r < 4; ++r)
                    s2[rb + lk * 4 + r][col] = f2bf(fmaxf(acc[f][r] + bv, 0.f));
            }
        }
        __syncthreads();

        // stage 3: q3 (K=96 pad, N=256 = 16 frags; 8 per col group)
        {
            f32x4 acc[8];
            #pragma unroll
            for (int f = 0; f < 8; ++f) acc[f] = (f32x4){0.f, 0.f, 0.f, 0.f};
            #pragma unroll
            for (int ks = 0; ks < 3; ++ks) {
                const short8v a = *(const short8v*)&s2[rb + lr][lk * 8 + ks * 32];
                #pragma unroll
                for (int f = 0; f < 8; ++f) {
                    const int cf = cg * 8 + f;
                    const short8v b = *(const short8v*)(w5t + (size_t)(cf * 16 + lr) * 96
                                                            + lk * 8 + ks * 32);
                    acc[f] = __builtin_amdgcn_mfma_f32_16x16x32_bf16(a, b, acc[f], 0, 0, 0);
                }
            }
            #pragma unroll
            for (int f = 0; f < 8; ++f) {
                const int col = (cg * 8 + f) * 16 + lr;
                const float bv = qb3[col];
                #pragma unroll
                for (int r = 0; r < 4; ++r)
                    qe[(size_t)(m0 + rb + lk * 4 + r) * 256 + col] = f2bf(acc[f][r] + bv);
            }
        }
    }
}

// ==================== KERNEL 3: prior transpose+log (own kernel, 16.6 KB LDS) ====================

__global__ __launch_bounds__(256) void prior_log_transpose(
    const float* __restrict__ prior, ushort* __restrict__ lgp)
{
    __shared__ float T[64][65];
    const int b    = blockIdx.z;
    const int t1_0 = blockIdx.x * 64;
    const int t2_0 = blockIdx.y * 64;
    const int j  = threadIdx.x & 63;
    const int i0 = (threadIdx.x >> 6) * 16;
    #pragma unroll
    for (int r = 0; r < 16; ++r)
        T[i0 + r][j] = __builtin_nontemporal_load(
            prior + ((size_t)b * TT2 + t2_0 + i0 + r) * TT1 + t1_0 + j);
    __syncthreads();
    #pragma unroll
    for (int r = 0; r < 16; ++r) {
        const int p = i0 + r;
        const float v = T[j][p];
        lgp[((size_t)b * TT1 + t1_0 + p) * TT2 + t2_0 + j] = f2bf(__logf(v + 1e-8f));
    }
}

// ==================== KERNEL 4: fused attention (round-8 verified) ====================

__global__ __launch_bounds__(512) void attn_kernel(
    const ushort* __restrict__ qe, const ushort* __restrict__ ke,
    const float* __restrict__ k2t, const ushort* __restrict__ lgp,
    const unsigned char* __restrict__ mask,
    float* __restrict__ out_attn, float* __restrict__ out_lp)
{
    __shared__ float S[16][516];
    __shared__ float rowZ[16];
    __shared__ float rowM[16];
    __shared__ float rowI[16];
    const int b    = blockIdx.x >> 7;
    const int t1_0 = (blockIdx.x & 127) << 4;
    const int tid  = threadIdx.x;
    const int lane = tid & 63;
    const int wv   = tid >> 6;
    const int t2   = tid;

    // ---- prefetch ----
    const bool mv = mask[(size_t)b * TT2 + t2] != 0;
    ushort lg[16];
    #pragma unroll
    for (int r = 0; r < 16; ++r)
        lg[r] = lgp[((size_t)b * TT1 + t1_0 + r) * TT2 + t2];

    // ---- phase 1: QK^T via MFMA, fold k2t ----
    {
        const int lr = lane & 15;
        const int lk = lane >> 4;
        const ushort* qrow = qe + ((size_t)b * TT1 + t1_0 + lr) * NATT + lk * 8;
        short8v a[8];
        #pragma unroll
        for (int k = 0; k < 8; ++k)
            a[k] = *(const short8v*)(qrow + k * 32);

        const ushort* kbase = ke + ((size_t)b * TT2 + wv * 64 + lr) * NATT + lk * 8;
        #pragma unroll
        for (int n = 0; n < 4; ++n) {
            f32x4 acc = {0.f, 0.f, 0.f, 0.f};
            const ushort* kb = kbase + (size_t)n * 16 * NATT;
            #pragma unroll
            for (int k = 0; k < 8; ++k) {
                short8v bfr = *(const short8v*)(kb + k * 32);
                acc = __builtin_amdgcn_mfma_f32_16x16x32_bf16(a[k], bfr, acc, 0, 0, 0);
            }
            const int col = wv * 64 + n * 16 + lr;
            const float k2v = k2t[(size_t)b * TT2 + col];
            #pragma unroll
            for (int r = 0; r < 4; ++r)
                S[lk * 4 + r][col] = fmaf(2.0f * TEMP, acc[r], k2v);
        }
    }
    __syncthreads();

    const int rr = tid >> 5;
    const int jj = tid & 31;

    // ---- phase 2a: logZ per row ----
    {
        float sv[16];
        #pragma unroll
        for (int k = 0; k < 16; ++k) sv[k] = S[rr][jj + 32 * k];
        float mx = sv[0];
        #pragma unroll
        for (int k = 1; k < 16; ++k) mx = fmaxf(mx, sv[k]);
        #pragma unroll
        for (int off = 16; off; off >>= 1) mx = fmaxf(mx, __shfl_xor(mx, off));
        float se = 0.f;
        #pragma unroll
        for (int k = 0; k < 16; ++k) se += __expf(sv[k] - mx);
        #pragma unroll
        for (int off = 16; off; off >>= 1) se += __shfl_xor(se, off);
        if (jj == 0) rowZ[rr] = mx + __logf(se);
    }
    __syncthreads();

    // ---- phase 2b: lp store, U (masked) -> LDS ----
    #pragma unroll
    for (int r = 0; r < 16; ++r) {
        const float uu = S[r][t2] + bf2f(lg[r]);
        out_lp[((size_t)b * TT1 + t1_0 + r) * TT2 + t2] = uu - rowZ[r];
        S[r][t2] = mv ? -INFINITY : uu;
    }
    __syncthreads();

    // ---- phase 2c: masked max + inv-sumexp per row ----
    {
        float uv[16];
        #pragma unroll
        for (int k = 0; k < 16; ++k) uv[k] = S[rr][jj + 32 * k];
        float mx = uv[0];
        #pragma unroll
        for (int k = 1; k < 16; ++k) mx = fmaxf(mx, uv[k]);
        #pragma unroll
        for (int off = 16; off; off >>= 1) mx = fmaxf(mx, __shfl_xor(mx, off));
        float se = 0.f;
        #pragma unroll
        for (int k = 0; k < 16; ++k) se += __expf(uv[k] - mx);
        #pragma unroll
        for (int off = 16; off; off >>= 1) se += __shfl_xor(se, off);
        if (jj == 0) { rowM[rr] = mx; rowI[rr] = 1.0f / se; }
    }
    __syncthreads();

    // ---- phase 2d: attn = exp(U - m2) * inv ----
    #pragma unroll
    for (int r = 0; r < 16; ++r) {
        const float a = __expf(S[r][t2] - rowM[r]) * rowI[r];
        out_attn[((size_t)b * TT1 + t1_0 + r) * TT2 + t2] = a;
    }
}

// ---------------- launch ----------------

extern "C" void kernel_launch(void* const* d_in, const int* in_sizes, int n_in,
                              void* d_out, int out_size, void* d_ws, size_t ws_size,
                              hipStream_t stream) {
    const float* queries = (const float*)d_in[0];   // (B, 80, 2048)
    const float* keys    = (const float*)d_in[1];   // (B, 512, 256)
    const unsigned char* mask = (const unsigned char*)d_in[2]; // (B, 512) bool
    const float* prior   = (const float*)d_in[3];   // (B, 512, 2048)
    const float* kw1 = (const float*)d_in[4];
    const float* kb1 = (const float*)d_in[5];
    const float* kw2 = (const float*)d_in[6];
    const float* kb2 = (const float*)d_in[7];
    const float* qw1 = (const float*)d_in[8];
    const float* qb1 = (const float*)d_in[9];
    const float* qw2 = (const float*)d_in[10];
    const float* qb2 = (const float*)d_in[11];
    const float* qw3 = (const float*)d_in[12];
    const float* qb3 = (const float*)d_in[13];

    ushort* us   = (ushort*)d_ws;
    ushort* kp   = us;
    ushort* ke   = kp  + KP_SZ;
    ushort* qp   = ke  + KE_SZ;
    ushort* qe   = qp  + QP_SZ;
    ushort* w1t  = qe  + QE_SZ;
    ushort* w2t  = w1t + W1T_SZ;
    ushort* w3t  = w2t + W2T_SZ;
    ushort* w4t  = w3t + W3T_SZ;
    ushort* w5t  = w4t + W4T_SZ;
    ushort* lgp  = w5t + W5T_SZ;
    float*  k2   = (float*)(lgp + LGP_SZ);

    float* out_attn = (float*)d_out;
    float* out_lp   = out_attn + (size_t)NB * TT1 * TT2;

    prep_kernel<<<PREP_PK_BLK + PREP_WT_BLK + PREP_QT_BLK, 256, 0, stream>>>(
        keys, kp, kw1, kw2, qw1, qw2, qw3, w1t, w2t, w3t, w4t, w5t, queries, qp);

    conv_kernel<<<CONV_KEY_BLK + CONV_QRY_BLK, 512, 0, stream>>>(
        kp, w1t, kb1, w2t, kb2, ke, k2,
        qp, w3t, qb1, w4t, qb2, w5t, qb3, qe);

    prior_log_transpose<<<dim3(TT1 / 64, TT2 / 64, NB), 256, 0, stream>>>(prior, lgp);

    attn_kernel<<<NB * (TT1 / 16), 512, 0, stream>>>(
        qe, ke, k2, lgp, mask, out_attn, out_lp);
}

// Round 14
// 177.356 us; speedup vs baseline: 1.5000x; 1.2268x over previous
//
#include <hip/hip_runtime.h>
#include <cmath>

#define NB    16
#define TT1   2048
#define TT2   512
#define NATT  256
#define TEMP  0.0005f

// workspace element counts (ushort = bf16 unless noted)
#define KP_SZ   (NB*514*256)        // padded keys (B, 514, 256)
#define KE_SZ   (NB*512*256)        // key proj out
#define QP_SZ   (NB*2050*80)        // padded transposed queries
#define QE_SZ   (NB*2048*256)
#define W1T_SZ  (512*768)
#define W2T_SZ  (256*512)
#define W3T_SZ  (160*256)
#define W4T_SZ  (80*160)
#define W5T_SZ  (256*96)
#define WTOT_SZ (W1T_SZ+W2T_SZ+W3T_SZ+W4T_SZ+W5T_SZ)
#define LGP_SZ  (NB*TT1*TT2)        // bf16 log(prior+eps), transposed [b][t1][t2]

// prep grid
#define PREP_PK_BLK   (KP_SZ/256)           // 8224
#define PREP_WT_BLK   (WTOT_SZ/256)         // 2354
#define PREP_QT_BLK   (NB*(TT1/64))         // 512
// conv grid
#define CONV_KEY_BLK  (NB*512/32)           // 256
#define CONV_QRY_BLK  (NB*2048/128)         // 256

typedef __attribute__((ext_vector_type(8))) short short8v;
typedef __attribute__((ext_vector_type(4))) float f32x4;

__device__ inline ushort f2bf(float f) {
    unsigned int u = __float_as_uint(f);
    u += 0x7fff + ((u >> 16) & 1);      // RNE
    return (ushort)(u >> 16);
}
__device__ inline float bf2f(ushort u) {
    return __uint_as_float(((unsigned int)u) << 16);
}

// ==================== KERNEL 1: prep (pad_keys | wtrans | query transpose) ====================

__global__ __launch_bounds__(256) void prep_kernel(
    const float* __restrict__ keys, ushort* __restrict__ kp,
    const float* __restrict__ kw1, const float* __restrict__ kw2,
    const float* __restrict__ qw1, const float* __restrict__ qw2,
    const float* __restrict__ qw3,
    ushort* __restrict__ w1t, ushort* __restrict__ w2t, ushort* __restrict__ w3t,
    ushort* __restrict__ w4t, ushort* __restrict__ w5t,
    const float* __restrict__ queries, ushort* __restrict__ qp)
{
    __shared__ float T[80][65];
    const int bx  = blockIdx.x;
    const int tid = threadIdx.x;

    if (bx < PREP_PK_BLK) {
        const int idx = bx * 256 + tid;
        int c = idx & 255;
        int r = (idx >> 8) % 514;
        int b = idx / (514 * 256);
        float v = 0.f;
        if (r >= 1 && r <= 512)
            v = keys[((size_t)b * 512 + (r - 1)) * 256 + c];
        kp[idx] = f2bf(v);
        return;
    }
    if (bx < PREP_PK_BLK + PREP_WT_BLK) {
        int idx = (bx - PREP_PK_BLK) * 256 + tid;
        const float* w; ushort* wt; int Kreal, Kpad, N;
        if (idx < W1T_SZ) {
            w = kw1; wt = w1t; Kreal = 768; Kpad = 768; N = 512;
        } else if ((idx -= W1T_SZ) < W2T_SZ) {
            w = kw2; wt = w2t; Kreal = 512; Kpad = 512; N = 256;
        } else if ((idx -= W2T_SZ) < W3T_SZ) {
            w = qw1; wt = w3t; Kreal = 240; Kpad = 256; N = 160;
        } else if ((idx -= W3T_SZ) < W4T_SZ) {
            w = qw2; wt = w4t; Kreal = 160; Kpad = 160; N = 80;
        } else {
            idx -= W4T_SZ;
            w = qw3; wt = w5t; Kreal = 80; Kpad = 96; N = 256;
        }
        int k = idx % Kpad;
        int n = idx / Kpad;
        wt[idx] = (k < Kreal) ? f2bf(w[(size_t)k * N + n]) : (ushort)0;
        return;
    }
    // ---- query transpose (LDS-tiled) ----
    {
        const int l  = bx - PREP_PK_BLK - PREP_WT_BLK;   // [0, 512)
        const int b  = l >> 5;
        const int t0 = (l & 31) * 64;
        const int g  = tid >> 6;
        const int j  = tid & 63;
        #pragma unroll
        for (int r = 0; r < 20; ++r) {
            const int c = g * 20 + r;
            T[c][j] = queries[((size_t)b * 80 + c) * 2048 + t0 + j];
        }
        __syncthreads();
        const int tt = tid >> 2;
        const int c0 = (tid & 3) * 20;
        ushort* qrow = qp + (size_t)b * (2050 * 80) + (size_t)(t0 + tt + 1) * 80 + c0;
        #pragma unroll
        for (int i4 = 0; i4 < 5; ++i4) {
            ushort4 st;
            st.x = f2bf(T[c0 + i4 * 4 + 0][tt]);
            st.y = f2bf(T[c0 + i4 * 4 + 1][tt]);
            st.z = f2bf(T[c0 + i4 * 4 + 2][tt]);
            st.w = f2bf(T[c0 + i4 * 4 + 3][tt]);
            *(ushort4*)(qrow + i4 * 4) = st;
        }
        if (t0 == 0 && tid < 80)
            qp[(size_t)b * (2050 * 80) + tid] = 0;
        if (t0 == 2048 - 64 && tid < 80)
            qp[(size_t)b * (2050 * 80) + (size_t)2049 * 80 + tid] = 0;
    }
}

// ==================== KERNEL 2: conv — rf=2 B-reuse, 8 waves/block ====================
// key role  (bx < 256): 32 t2-rows/block; s1: wave = 2 rowfrag x 4 colfrag (cols wv*64..)
// query role (bx >= 256): 128 t1-rows/block; wave = rowgroup (wv&3, 32 rows) x colhalf (wv>>2)

__global__ __launch_bounds__(512, 4) void conv_kernel(
    const ushort* __restrict__ kp, const ushort* __restrict__ w1t,
    const float* __restrict__ kb1, const ushort* __restrict__ w2t,
    const float* __restrict__ kb2, ushort* __restrict__ ke, float* __restrict__ k2,
    const ushort* __restrict__ qp, const ushort* __restrict__ w3t,
    const float* __restrict__ qb1, const ushort* __restrict__ w4t,
    const float* __restrict__ qb2, const ushort* __restrict__ w5t,
    const float* __restrict__ qb3, ushort* __restrict__ qe)
{
    __shared__ __align__(16) unsigned char smem[69632];
    const int bx   = blockIdx.x;
    const int tid  = threadIdx.x;
    const int wv   = tid >> 6;        // 0..7
    const int lane = tid & 63;
    const int lr   = lane & 15;
    const int lk   = lane >> 4;

    if (bx < CONV_KEY_BLK) {
        // ---------------- key role ----------------
        ushort (*h1s)[536] = (ushort(*)[536])smem;           // 34304 B
        float (*k2part)[8] = (float(*)[8])(smem + 32 * 536 * 2);
        const int m0 = bx * 32;

        // stage 1: K=768, N=512; wave cols [wv*64,+64), rows 2x16
        {
            const ushort* arow0;
            const ushort* arow1;
            {
                const int m = m0 + lr;
                arow0 = kp + (size_t)(m >> 9) * (514 * 256) + (size_t)(m & 511) * 256 + lk * 8;
                const int m1 = m0 + 16 + lr;
                arow1 = kp + (size_t)(m1 >> 9) * (514 * 256) + (size_t)(m1 & 511) * 256 + lk * 8;
            }
            const ushort* wtb = w1t + (size_t)(wv * 64 + lr) * 768 + lk * 8;
            f32x4 acc[2][4];
            #pragma unroll
            for (int mf = 0; mf < 2; ++mf)
                #pragma unroll
                for (int f = 0; f < 4; ++f) acc[mf][f] = (f32x4){0.f, 0.f, 0.f, 0.f};
            #pragma unroll
            for (int ks = 0; ks < 24; ++ks) {
                const short8v a0 = *(const short8v*)(arow0 + ks * 32);
                const short8v a1 = *(const short8v*)(arow1 + ks * 32);
                #pragma unroll
                for (int f = 0; f < 4; ++f) {
                    const short8v b = *(const short8v*)(wtb + (size_t)f * 16 * 768 + ks * 32);
                    acc[0][f] = __builtin_amdgcn_mfma_f32_16x16x32_bf16(a0, b, acc[0][f], 0, 0, 0);
                    acc[1][f] = __builtin_amdgcn_mfma_f32_16x16x32_bf16(a1, b, acc[1][f], 0, 0, 0);
                }
            }
            #pragma unroll
            for (int f = 0; f < 4; ++f) {
                const int col = wv * 64 + f * 16 + lr;
                const float bv = kb1[col];
                #pragma unroll
                for (int mf = 0; mf < 2; ++mf)
                    #pragma unroll
                    for (int r = 0; r < 4; ++r)
                        h1s[mf * 16 + lk * 4 + r][col] = f2bf(fmaxf(acc[mf][f][r] + bv, 0.f));
            }
        }
        __syncthreads();

        // stage 2: K=512 (LDS), N=256; wave cols [wv*32,+32), rows 2x16; k2 folded
        {
            f32x4 acc[2][2];
            #pragma unroll
            for (int mf = 0; mf < 2; ++mf)
                #pragma unroll
                for (int f = 0; f < 2; ++f) acc[mf][f] = (f32x4){0.f, 0.f, 0.f, 0.f};
            #pragma unroll
            for (int ks = 0; ks < 16; ++ks) {
                const short8v a0 = *(const short8v*)&h1s[lr][lk * 8 + ks * 32];
                const short8v a1 = *(const short8v*)&h1s[16 + lr][lk * 8 + ks * 32];
                #pragma unroll
                for (int f = 0; f < 2; ++f) {
                    const short8v b = *(const short8v*)(w2t + (size_t)(wv * 32 + f * 16 + lr) * 512
                                                            + lk * 8 + ks * 32);
                    acc[0][f] = __builtin_amdgcn_mfma_f32_16x16x32_bf16(a0, b, acc[0][f], 0, 0, 0);
                    acc[1][f] = __builtin_amdgcn_mfma_f32_16x16x32_bf16(a1, b, acc[1][f], 0, 0, 0);
                }
            }
            float ss[2][4];
            #pragma unroll
            for (int mf = 0; mf < 2; ++mf)
                #pragma unroll
                for (int r = 0; r < 4; ++r) ss[mf][r] = 0.f;
            #pragma unroll
            for (int f = 0; f < 2; ++f) {
                const int col = wv * 32 + f * 16 + lr;
                const float bv = kb2[col];
                #pragma unroll
                for (int mf = 0; mf < 2; ++mf)
                    #pragma unroll
                    for (int r = 0; r < 4; ++r) {
                        const float o = acc[mf][f][r] + bv;
                        ke[(size_t)(m0 + mf * 16 + lk * 4 + r) * 256 + col] = f2bf(o);
                        ss[mf][r] += o * o;
                    }
            }
            #pragma unroll
            for (int mf = 0; mf < 2; ++mf)
                #pragma unroll
                for (int r = 0; r < 4; ++r) {
                    #pragma unroll
                    for (int off = 1; off < 16; off <<= 1)
                        ss[mf][r] += __shfl_xor(ss[mf][r], off);
                }
            if (lr == 0) {
                #pragma unroll
                for (int mf = 0; mf < 2; ++mf)
                    #pragma unroll
                    for (int r = 0; r < 4; ++r)
                        k2part[mf * 16 + lk * 4 + r][wv] = ss[mf][r];
            }
        }
        __syncthreads();
        if (tid < 32) {
            float s = 0.f;
            #pragma unroll
            for (int w = 0; w < 8; ++w) s += k2part[tid][w];
            k2[m0 + tid] = -TEMP * s;
        }
        return;
    }
    // ---------------- query role ----------------
    {
        ushort (*s1)[168] = (ushort(*)[168])smem;            // 43008 B
        ushort (*s2)[104] = (ushort(*)[104])(smem + 128 * 168 * 2);  // 26624 B
        const int m0 = (bx - CONV_KEY_BLK) * 128;
        const int cg = wv >> 2;           // col half
        const int rb = (wv & 3) * 32;     // row base (2 row-frags)

        // zero s2 cols [80,96): 128 rows x 16 = 2048 over 512 thr
        #pragma unroll
        for (int i = 0; i < 4; ++i) {
            const int e = tid * 4 + i;
            s2[e >> 4][80 + (e & 15)] = 0;
        }

        // stage q1: K=256pad, N=160; cg covers 5 col-frags; rows 2x16
        {
            const ushort* arow0;
            const ushort* arow1;
            {
                const int m = m0 + rb + lr;
                arow0 = qp + (size_t)(m >> 11) * (2050 * 80) + (size_t)(m & 2047) * 80 + lk * 8;
                const int m1 = m0 + rb + 16 + lr;
                arow1 = qp + (size_t)(m1 >> 11) * (2050 * 80) + (size_t)(m1 & 2047) * 80 + lk * 8;
            }
            f32x4 acc[2][5];
            #pragma unroll
            for (int mf = 0; mf < 2; ++mf)
                #pragma unroll
                for (int f = 0; f < 5; ++f) acc[mf][f] = (f32x4){0.f, 0.f, 0.f, 0.f};
            #pragma unroll
            for (int ks = 0; ks < 8; ++ks) {
                const short8v a0 = *(const short8v*)(arow0 + ks * 32);
                const short8v a1 = *(const short8v*)(arow1 + ks * 32);
                #pragma unroll
                for (int f = 0; f < 5; ++f) {
                    const short8v b = *(const short8v*)(w3t + (size_t)((cg * 5 + f) * 16 + lr) * 256
                                                            + lk * 8 + ks * 32);
                    acc[0][f] = __builtin_amdgcn_mfma_f32_16x16x32_bf16(a0, b, acc[0][f], 0, 0, 0);
                    acc[1][f] = __builtin_amdgcn_mfma_f32_16x16x32_bf16(a1, b, acc[1][f], 0, 0, 0);
                }
            }
            #pragma unroll
            for (int f = 0; f < 5; ++f) {
                const int col = (cg * 5 + f) * 16 + lr;
                const float bv = qb1[col];
                #pragma unroll
                for (int mf = 0; mf < 2; ++mf)
                    #pragma unroll
                    for (int r = 0; r < 4; ++r)
                        s1[rb + mf * 16 + lk * 4 + r][col] = f2bf(fmaxf(acc[mf][f][r] + bv, 0.f));
            }
        }
        __syncthreads();

        // stage q2: K=160, N=80 (5 frags: cg0 -> 3, cg1 -> 2); rows 2x16
        {
            const int nf = cg ? 2 : 3;
            const int f0 = cg ? 3 : 0;
            f32x4 acc[2][3];
            #pragma unroll
            for (int mf = 0; mf < 2; ++mf)
                #pragma unroll
                for (int f = 0; f < 3; ++f) acc[mf][f] = (f32x4){0.f, 0.f, 0.f, 0.f};
            #pragma unroll
            for (int ks = 0; ks < 5; ++ks) {
                const short8v a0 = *(const short8v*)&s1[rb + lr][lk * 8 + ks * 32];
                const short8v a1 = *(const short8v*)&s1[rb + 16 + lr][lk * 8 + ks * 32];
                #pragma unroll
                for (int f = 0; f < 3; ++f) {
                    if (f < nf) {
                        const short8v b = *(const short8v*)(w4t + (size_t)((f0 + f) * 16 + lr) * 160
                                                                + lk * 8 + ks * 32);
                        acc[0][f] = __builtin_amdgcn_mfma_f32_16x16x32_bf16(a0, b, acc[0][f], 0, 0, 0);
                        acc[1][f] = __builtin_amdgcn_mfma_f32_16x16x32_bf16(a1, b, acc[1][f], 0, 0, 0);
                    }
                }
            }
            #pragma unroll
            for (int f = 0; f < 3; ++f) {
                if (f < nf) {
                    const int col = (f0 + f) * 16 + lr;
                    const float bv = qb2[col];
                    #pragma unroll
                    for (int mf = 0; mf < 2; ++mf)
                        #pragma unroll
                        for (int r = 0; r < 4; ++r)
                            s2[rb + mf * 16 + lk * 4 + r][col] = f2bf(fmaxf(acc[mf][f][r] + bv, 0.f));
                }
            }
        }
        __syncthreads();

        // stage q3: K=96pad, N=256 (16 frags: 8 per cg); rows 2x16
        {
            f32x4 acc[2][8];
            #pragma unroll
            for (int mf = 0; mf < 2; ++mf)
                #pragma unroll
                for (int f = 0; f < 8; ++f) acc[mf][f] = (f32x4){0.f, 0.f, 0.f, 0.f};
            #pragma unroll
            for (int ks = 0; ks < 3; ++ks) {
                const short8v a0 = *(const short8v*)&s2[rb + lr][lk * 8 + ks * 32];
                const short8v a1 = *(const short8v*)&s2[rb + 16 + lr][lk * 8 + ks * 32];
                #pragma unroll
                for (int f = 0; f < 8; ++f) {
                    const short8v b = *(const short8v*)(w5t + (size_t)((cg * 8 + f) * 16 + lr) * 96
                                                            + lk * 8 + ks * 32);
                    acc[0][f] = __builtin_amdgcn_mfma_f32_16x16x32_bf16(a0, b, acc[0][f], 0, 0, 0);
                    acc[1][f] = __builtin_amdgcn_mfma_f32_16x16x32_bf16(a1, b, acc[1][f], 0, 0, 0);
                }
            }
            #pragma unroll
            for (int f = 0; f < 8; ++f) {
                const int col = (cg * 8 + f) * 16 + lr;
                const float bv = qb3[col];
                #pragma unroll
                for (int mf = 0; mf < 2; ++mf)
                    #pragma unroll
                    for (int r = 0; r < 4; ++r)
                        qe[(size_t)(m0 + rb + mf * 16 + lk * 4 + r) * 256 + col] = f2bf(acc[mf][f][r] + bv);
            }
        }
    }
}

// ==================== KERNEL 3: prior transpose+log ====================

__global__ __launch_bounds__(256) void prior_log_transpose(
    const float* __restrict__ prior, ushort* __restrict__ lgp)
{
    __shared__ float T[64][65];
    const int b    = blockIdx.z;
    const int t1_0 = blockIdx.x * 64;
    const int t2_0 = blockIdx.y * 64;
    const int j  = threadIdx.x & 63;
    const int i0 = (threadIdx.x >> 6) * 16;
    #pragma unroll
    for (int r = 0; r < 16; ++r)
        T[i0 + r][j] = __builtin_nontemporal_load(
            prior + ((size_t)b * TT2 + t2_0 + i0 + r) * TT1 + t1_0 + j);
    __syncthreads();
    #pragma unroll
    for (int r = 0; r < 16; ++r) {
        const int p = i0 + r;
        const float v = T[j][p];
        lgp[((size_t)b * TT1 + t1_0 + p) * TT2 + t2_0 + j] = f2bf(__logf(v + 1e-8f));
    }
}

// ==================== KERNEL 4: fused attention (round-8 verified) ====================

__global__ __launch_bounds__(512) void attn_kernel(
    const ushort* __restrict__ qe, const ushort* __restrict__ ke,
    const float* __restrict__ k2t, const ushort* __restrict__ lgp,
    const unsigned char* __restrict__ mask,
    float* __restrict__ out_attn, float* __restrict__ out_lp)
{
    __shared__ float S[16][516];
    __shared__ float rowZ[16];
    __shared__ float rowM[16];
    __shared__ float rowI[16];
    const int b    = blockIdx.x >> 7;
    const int t1_0 = (blockIdx.x & 127) << 4;
    const int tid  = threadIdx.x;
    const int lane = tid & 63;
    const int wv   = tid >> 6;
    const int t2   = tid;

    // ---- prefetch ----
    const bool mv = mask[(size_t)b * TT2 + t2] != 0;
    ushort lg[16];
    #pragma unroll
    for (int r = 0; r < 16; ++r)
        lg[r] = lgp[((size_t)b * TT1 + t1_0 + r) * TT2 + t2];

    // ---- phase 1: QK^T via MFMA, fold k2t ----
    {
        const int lr = lane & 15;
        const int lk = lane >> 4;
        const ushort* qrow = qe + ((size_t)b * TT1 + t1_0 + lr) * NATT + lk * 8;
        short8v a[8];
        #pragma unroll
        for (int k = 0; k < 8; ++k)
            a[k] = *(const short8v*)(qrow + k * 32);

        const ushort* kbase = ke + ((size_t)b * TT2 + wv * 64 + lr) * NATT + lk * 8;
        #pragma unroll
        for (int n = 0; n < 4; ++n) {
            f32x4 acc = {0.f, 0.f, 0.f, 0.f};
            const ushort* kb = kbase + (size_t)n * 16 * NATT;
            #pragma unroll
            for (int k = 0; k < 8; ++k) {
                short8v bfr = *(const short8v*)(kb + k * 32);
                acc = __builtin_amdgcn_mfma_f32_16x16x32_bf16(a[k], bfr, acc, 0, 0, 0);
            }
            const int col = wv * 64 + n * 16 + lr;
            const float k2v = k2t[(size_t)b * TT2 + col];
            #pragma unroll
            for (int r = 0; r < 4; ++r)
                S[lk * 4 + r][col] = fmaf(2.0f * TEMP, acc[r], k2v);
        }
    }
    __syncthreads();

    const int rr = tid >> 5;
    const int jj = tid & 31;

    // ---- phase 2a: logZ per row ----
    {
        float sv[16];
        #pragma unroll
        for (int k = 0; k < 16; ++k) sv[k] = S[rr][jj + 32 * k];
        float mx = sv[0];
        #pragma unroll
        for (int k = 1; k < 16; ++k) mx = fmaxf(mx, sv[k]);
        #pragma unroll
        for (int off = 16; off; off >>= 1) mx = fmaxf(mx, __shfl_xor(mx, off));
        float se = 0.f;
        #pragma unroll
        for (int k = 0; k < 16; ++k) se += __expf(sv[k] - mx);
        #pragma unroll
        for (int off = 16; off; off >>= 1) se += __shfl_xor(se, off);
        if (jj == 0) rowZ[rr] = mx + __logf(se);
    }
    __syncthreads();

    // ---- phase 2b: lp store, U (masked) -> LDS ----
    #pragma unroll
    for (int r = 0; r < 16; ++r) {
        const float uu = S[r][t2] + bf2f(lg[r]);
        out_lp[((size_t)b * TT1 + t1_0 + r) * TT2 + t2] = uu - rowZ[r];
        S[r][t2] = mv ? -INFINITY : uu;
    }
    __syncthreads();

    // ---- phase 2c: masked max + inv-sumexp per row ----
    {
        float uv[16];
        #pragma unroll
        for (int k = 0; k < 16; ++k) uv[k] = S[rr][jj + 32 * k];
        float mx = uv[0];
        #pragma unroll
        for (int k = 1; k < 16; ++k) mx = fmaxf(mx, uv[k]);
        #pragma unroll
        for (int off = 16; off; off >>= 1) mx = fmaxf(mx, __shfl_xor(mx, off));
        float se = 0.f;
        #pragma unroll
        for (int k = 0; k < 16; ++k) se += __expf(uv[k] - mx);
        #pragma unroll
        for (int off = 16; off; off >>= 1) se += __shfl_xor(se, off);
        if (jj == 0) { rowM[rr] = mx; rowI[rr] = 1.0f / se; }
    }
    __syncthreads();

    // ---- phase 2d: attn = exp(U - m2) * inv ----
    #pragma unroll
    for (int r = 0; r < 16; ++r) {
        const float a = __expf(S[r][t2] - rowM[r]) * rowI[r];
        out_attn[((size_t)b * TT1 + t1_0 + r) * TT2 + t2] = a;
    }
}

// ---------------- launch ----------------

extern "C" void kernel_launch(void* const* d_in, const int* in_sizes, int n_in,
                              void* d_out, int out_size, void* d_ws, size_t ws_size,
                              hipStream_t stream) {
    const float* queries = (const float*)d_in[0];   // (B, 80, 2048)
    const float* keys    = (const float*)d_in[1];   // (B, 512, 256)
    const unsigned char* mask = (const unsigned char*)d_in[2]; // (B, 512) bool
    const float* prior   = (const float*)d_in[3];   // (B, 512, 2048)
    const float* kw1 = (const float*)d_in[4];
    const float* kb1 = (const float*)d_in[5];
    const float* kw2 = (const float*)d_in[6];
    const float* kb2 = (const float*)d_in[7];
    const float* qw1 = (const float*)d_in[8];
    const float* qb1 = (const float*)d_in[9];
    const float* qw2 = (const float*)d_in[10];
    const float* qb2 = (const float*)d_in[11];
    const float* qw3 = (const float*)d_in[12];
    const float* qb3 = (const float*)d_in[13];

    ushort* us   = (ushort*)d_ws;
    ushort* kp   = us;
    ushort* ke   = kp  + KP_SZ;
    ushort* qp   = ke  + KE_SZ;
    ushort* qe   = qp  + QP_SZ;
    ushort* w1t  = qe  + QE_SZ;
    ushort* w2t  = w1t + W1T_SZ;
    ushort* w3t  = w2t + W2T_SZ;
    ushort* w4t  = w3t + W3T_SZ;
    ushort* w5t  = w4t + W4T_SZ;
    ushort* lgp  = w5t + W5T_SZ;
    float*  k2   = (float*)(lgp + LGP_SZ);

    float* out_attn = (float*)d_out;
    float* out_lp   = out_attn + (size_t)NB * TT1 * TT2;

    prep_kernel<<<PREP_PK_BLK + PREP_WT_BLK + PREP_QT_BLK, 256, 0, stream>>>(
        keys, kp, kw1, kw2, qw1, qw2, qw3, w1t, w2t, w3t, w4t, w5t, queries, qp);

    conv_kernel<<<CONV_KEY_BLK + CONV_QRY_BLK, 512, 0, stream>>>(
        kp, w1t, kb1, w2t, kb2, ke, k2,
        qp, w3t, qb1, w4t, qb2, w5t, qb3, qe);

    prior_log_transpose<<<dim3(TT1 / 64, TT2 / 64, NB), 256, 0, stream>>>(prior, lgp);

    attn_kernel<<<NB * (TT1 / 16), 512, 0, stream>>>(
        qe, ke, k2, lgp, mask, out_attn, out_lp);
}